// Round 5
// baseline (207.273 us; speedup 1.0000x reference)
//
#include <hip/hip_runtime.h>
#include <hip/hip_bf16.h>

// ---------------------------------------------------------------------------
// GAT 2-layer forward. N=50000, E=800000 (+N self loops).
// Round 18: collapse the CSR build from 4 dispatches to 2. The count+scan+
// scatter trio is replaced by ONE kernel: per-block LDS histogram of its
// 1024-edge chunk (edges staged in LDS, ei read once), one device atomicAdd
// per (block,bucket) claims a sub-range of the fixed-stride bucket array
// bkt2[b*CAP] (CAP=6144 ~ 27 sigma above Poisson(4343) bucket load), then
// LDS-cursor scatter. Sort reads its bucket's strided range; csr4/rowptr
// unchanged in structure. Cursors zeroed via hipMemsetAsync (graph-safe).
// Within-row edge order becomes nondeterministic -> FP sum order permutes
// only (3.9x absmax headroom). Chain: memset -> scatter+cvt -> sort||gemm1
// -> aggr1 -> gemm2 -> aggr2 (5 kernels, was 7).
// R17 carried: wave-uniform shfl edge preload in aggregators. R14: in-lane
// softmax weights, fused-score GEMMs, packed 4B csr. Assumes N <= 65536.
// ---------------------------------------------------------------------------

typedef __attribute__((ext_vector_type(8))) short bf16x8;
typedef __attribute__((ext_vector_type(4))) float f32x4;

#define BCHUNK 1024

__device__ __forceinline__ unsigned short f2bf(float f) {
  unsigned x = __float_as_uint(f);
  unsigned r = (x + 0x7fffu + ((x >> 16) & 1u)) >> 16;  // RNE
  return (unsigned short)r;
}
__device__ __forceinline__ float bf2f(unsigned short u) {
  return __uint_as_float(((unsigned)u) << 16);
}
__device__ __forceinline__ float bflo(unsigned u) {
  return __uint_as_float(u << 16);
}
__device__ __forceinline__ float bfhi(unsigned u) {
  return __uint_as_float(u & 0xffff0000u);
}

// inclusive 256-scan in LDS; returns inclusive sum at tid.
__device__ __forceinline__ int lds_scan256(int v, int* s) {
  int tid = threadIdx.x;
  s[tid] = v;
  __syncthreads();
  for (int o = 1; o < 256; o <<= 1) {
    int t = (tid >= o) ? s[tid - o] : 0;
    __syncthreads();
    s[tid] += t;
    __syncthreads();
  }
  return s[tid];
}

// ---- K1: single-pass binned scatter + weight conversion --------------------
// blocks [0,NBLK): stage chunk in LDS -> histogram -> claim ranges via one
// device atomicAdd per (block,bucket) -> LDS-cursor scatter into bkt2.
// blocks [NBLK, NBLK+112): W1t/W2t transpose-convert + score-weight project.
__global__ __launch_bounds__(256) void b_scatter_cvt(
    const int* __restrict__ ei, int E, int N, int NBLK, int CAP,
    int* __restrict__ cur, unsigned* __restrict__ bkt2,
    const float* __restrict__ W1, const float* __restrict__ as1,
    const float* __restrict__ ad1, const float* __restrict__ W2,
    const float* __restrict__ as2, const float* __restrict__ ad2,
    unsigned short* __restrict__ W1t, unsigned short* __restrict__ W2t,
    unsigned short* __restrict__ wsb1, unsigned short* __restrict__ wsb2) {
  int tid = threadIdx.x;
  if ((int)blockIdx.x >= NBLK) {  // conversion blocks
    int i = ((int)blockIdx.x - NBLK) * 256 + tid;
    if (i < 16384) {                       // W1t
      int k = i >> 7, m = i & 127;
      W1t[m * 128 + k] = f2bf(W1[i]);
    } else if (i < 24576) {                // W2t
      int j = i - 16384;
      int k = j / 64, m = j % 64;
      W2t[m * 128 + k] = f2bf(W2[j]);
    } else if (i < 26624) {                // wsb1
      int j = i - 24576;
      int m = j >> 7, k = j & 127;
      float acc = 0.f;
      if (m < 4) {
        for (int c = 0; c < 32; ++c) acc += W1[k * 128 + m * 32 + c] * as1[m * 32 + c];
      } else if (m < 8) {
        for (int c = 0; c < 32; ++c) acc += W1[k * 128 + (m - 4) * 32 + c] * ad1[(m - 4) * 32 + c];
      }
      wsb1[j] = f2bf(acc);
    } else if (i < 28672) {                // wsb2
      int j = i - 26624;
      int m = j >> 7, k = j & 127;
      float acc = 0.f;
      if (m == 0) {
        for (int c = 0; c < 64; ++c) acc += W2[k * 64 + c] * as2[c];
      } else if (m == 1) {
        for (int c = 0; c < 64; ++c) acc += W2[k * 64 + c] * ad2[c];
      }
      wsb2[j] = f2bf(acc);
    }
    return;
  }
  __shared__ unsigned pk[BCHUNK];
  __shared__ unsigned char bk[BCHUNK];
  __shared__ int h[256];
  __shared__ int lcur[256];
  h[tid] = 0;
  __syncthreads();
  int ET = E + N;
  int base = blockIdx.x * BCHUNK;
  int lim = base + BCHUNK;
  if (lim > ET) lim = ET;
  int i = base + tid * 4;
  if (i + 3 < E && i + 4 <= lim) {
    int4 s4 = *(const int4*)(ei + i);
    int4 d4 = *(const int4*)(ei + E + i);
    int o = i - base;
    pk[o + 0] = (unsigned)s4.x | ((unsigned)(d4.x & 255) << 16);
    bk[o + 0] = (unsigned char)(d4.x >> 8); atomicAdd(&h[d4.x >> 8], 1);
    pk[o + 1] = (unsigned)s4.y | ((unsigned)(d4.y & 255) << 16);
    bk[o + 1] = (unsigned char)(d4.y >> 8); atomicAdd(&h[d4.y >> 8], 1);
    pk[o + 2] = (unsigned)s4.z | ((unsigned)(d4.z & 255) << 16);
    bk[o + 2] = (unsigned char)(d4.z >> 8); atomicAdd(&h[d4.z >> 8], 1);
    pk[o + 3] = (unsigned)s4.w | ((unsigned)(d4.w & 255) << 16);
    bk[o + 3] = (unsigned char)(d4.w >> 8); atomicAdd(&h[d4.w >> 8], 1);
  } else {
    for (int k = 0; k < 4; ++k) {
      int idx = i + k;
      if (idx < lim) {
        int s_, d;
        if (idx < E) { s_ = ei[idx]; d = ei[E + idx]; }
        else { s_ = idx - E; d = s_; }
        int o = idx - base;
        pk[o] = (unsigned)s_ | ((unsigned)(d & 255) << 16);
        bk[o] = (unsigned char)(d >> 8);
        atomicAdd(&h[d >> 8], 1);
      }
    }
  }
  __syncthreads();
  // claim per-bucket sub-range (device-scope atomic on global cursor)
  lcur[tid] = tid * CAP + atomicAdd(&cur[tid], h[tid]);
  __syncthreads();
  int cnt_ = lim - base;
  for (int o = tid; o < cnt_; o += 256) {
    int slot = atomicAdd(&lcur[bk[o]], 1);
    bkt2[slot] = pk[o];
  }
}

// ---- MFMA GEMM + fused scores (device body) --------------------------------
// C[N][M] bf16 = A @ Bt^T; scores = A @ wsb. row0 fully resolved per wave.
template <int AF32, int SC>
__device__ __forceinline__ void gemm_body(
    const void* __restrict__ Av, const unsigned short* __restrict__ Bt,
    const unsigned short* __restrict__ wsb, unsigned short* __restrict__ C,
    float* __restrict__ ssrc, float* __restrict__ sdst, int M, int row0) {
  const int K = 128;
  int lane = threadIdx.x & 63;
  int r = lane & 15, quad = lane >> 4;

  bf16x8 a[4];
  if (AF32) {
    const float* ap = (const float*)Av + (size_t)(row0 + r) * K + quad * 8;
#pragma unroll
    for (int t = 0; t < 4; ++t) {
      float4 lo = *(const float4*)(ap + t * 32);
      float4 hi = *(const float4*)(ap + t * 32 + 4);
      a[t][0] = (short)f2bf(lo.x); a[t][1] = (short)f2bf(lo.y);
      a[t][2] = (short)f2bf(lo.z); a[t][3] = (short)f2bf(lo.w);
      a[t][4] = (short)f2bf(hi.x); a[t][5] = (short)f2bf(hi.y);
      a[t][6] = (short)f2bf(hi.z); a[t][7] = (short)f2bf(hi.w);
    }
  } else {
    const unsigned short* ap = (const unsigned short*)Av + (size_t)(row0 + r) * K + quad * 8;
#pragma unroll
    for (int t = 0; t < 4; ++t) a[t] = *(const bf16x8*)(ap + t * 32);
  }

  for (int c0 = 0; c0 < M; c0 += 16) {
    f32x4 acc = {0.f, 0.f, 0.f, 0.f};
    const unsigned short* bp = Bt + (size_t)(c0 + r) * K + quad * 8;
#pragma unroll
    for (int t = 0; t < 4; ++t) {
      bf16x8 b = *(const bf16x8*)(bp + t * 32);
      acc = __builtin_amdgcn_mfma_f32_16x16x32_bf16(a[t], b, acc, 0, 0, 0);
    }
    unsigned short* cp = C + (size_t)(row0 + quad * 4) * M + c0 + r;
#pragma unroll
    for (int i = 0; i < 4; ++i) cp[(size_t)i * M] = f2bf(acc[i]);
  }

  // fused score tile: cols are wsb rows (0..SC-1 src, SC..2SC-1 dst)
  {
    f32x4 acc = {0.f, 0.f, 0.f, 0.f};
    const unsigned short* bp = wsb + r * 128 + quad * 8;
#pragma unroll
    for (int t = 0; t < 4; ++t) {
      bf16x8 b = *(const bf16x8*)(bp + t * 32);
      acc = __builtin_amdgcn_mfma_f32_16x16x32_bf16(a[t], b, acc, 0, 0, 0);
    }
    int row = row0 + quad * 4;
    if (r < SC) {
#pragma unroll
      for (int i = 0; i < 4; ++i) ssrc[(size_t)(row + i) * SC + r] = acc[i];
    } else if (r < 2 * SC) {
#pragma unroll
      for (int i = 0; i < 4; ++i) sdst[(size_t)(row + i) * SC + (r - SC)] = acc[i];
    }
  }
}

// standalone GEMM (layer 2)
template <int AF32, int SC>
__global__ __launch_bounds__(256) void gemm_mfma(
    const void* __restrict__ Av, const unsigned short* __restrict__ Bt,
    const unsigned short* __restrict__ wsb, unsigned short* __restrict__ C,
    float* __restrict__ ssrc, float* __restrict__ sdst, int N, int M) {
  int row0 = blockIdx.x * 64 + (threadIdx.x >> 6) * 16;
  if (row0 >= N) return;  // N % 16 == 0
  gemm_body<AF32, SC>(Av, Bt, wsb, C, ssrc, sdst, M, row0);
}

// ---- K2: bucket sort (from strided bkt2) || gemm1 --------------------------
// blocks [0,NBKT): LDS count+scan over the bucket's 256 nodes, coalesced
// rowptr write, block-local scatter into packed csr4.
// blocks [NBKT, NBKT+GB): full gemm1.
__global__ __launch_bounds__(256) void k_sort_gemm1(
    const unsigned* __restrict__ bkt2, int CAP, const int* __restrict__ cur,
    unsigned* __restrict__ csr4, int* __restrict__ rowptr, int N, int ET,
    int NBKT,
    const float* __restrict__ x, const unsigned short* __restrict__ W1t,
    const unsigned short* __restrict__ wsb1, unsigned short* __restrict__ h1b,
    float* __restrict__ ssrc1, float* __restrict__ sdst1) {
  if ((int)blockIdx.x >= NBKT) {
    int row0 = ((int)blockIdx.x - NBKT) * 64 + (threadIdx.x >> 6) * 16;
    if (row0 >= N) return;
    gemm_body<1, 4>(x, W1t, wsb1, h1b, ssrc1, sdst1, 128, row0);
    return;
  }
  __shared__ int s[256];
  __shared__ int cnt[256];
  int b = blockIdx.x, tid = threadIdx.x;
  int tot = cur[tid];  // per-bucket totals (buckets >= NBKT stayed 0)
  (void)lds_scan256(tot, s);  // s[i] = inclusive sum -> csr4 bases
  int base = (b == 0) ? 0 : s[b - 1];
  int tb = s[b] - base;
  const unsigned* src = bkt2 + (size_t)b * CAP;
  __syncthreads();
  cnt[tid] = 0;
  __syncthreads();
  for (int k = tid; k < tb; k += 512) {
    unsigned p0 = src[k];
    int k1 = k + 256;
    unsigned p1 = (k1 < tb) ? src[k1] : 0u;
    atomicAdd(&cnt[p0 >> 16], 1);
    if (k1 < tb) atomicAdd(&cnt[p1 >> 16], 1);
  }
  __syncthreads();
  int v = cnt[tid];
  int incl = lds_scan256(v, s);
  int excl = incl - v;
  int node = (b << 8) + tid;
  if (node < N) rowptr[node] = base + excl;
  if (tid == 0 && b == NBKT - 1) rowptr[N] = ET;
  cnt[tid] = base + excl;  // becomes the scatter cursor
  __syncthreads();
  for (int k = tid; k < tb; k += 512) {
    unsigned p0 = src[k];
    int k1 = k + 256;
    unsigned p1 = (k1 < tb) ? src[k1] : 0u;
    int slot0 = atomicAdd(&cnt[p0 >> 16], 1);
    csr4[slot0] = p0;
    if (k1 < tb) {
      int slot1 = atomicAdd(&cnt[p1 >> 16], 1);
      csr4[slot1] = p1;
    }
  }
}

// ---- aggregator: out[n] = (sum_e w_e * h[src_e]) / (sum_e w_e) + bias -------
// One wave per dst node. L lanes/edge, 8 bf16 channels/lane (uint4 gather);
// G=64/L edge groups in flight. The node's csr4 entries (first 64) are
// preloaded in ONE coalesced load. Trip count T=ceil(cnt/G) is wave-uniform,
// so every __shfl executes with a full exec mask; per-edge validity (j<cnt)
// predicates only the consuming gathers/FMAs. cnt>64 tail: direct load.
template <int H, int C, int L, int OUT_BF16>
__global__ __launch_bounds__(256) void gat_aggr4(
    const int* __restrict__ rowptr, const unsigned* __restrict__ csr4,
    const float* __restrict__ ssrc, const float* __restrict__ sdst,
    const unsigned short* __restrict__ h, const float* __restrict__ bias,
    void* __restrict__ outv, int N) {
  const int HC = H * C;  // = 8*L
  const int G = 64 / L;
  int lane = threadIdx.x & 63;
  int n = blockIdx.x * 4 + (threadIdx.x >> 6);
  if (n >= N) return;
  int l = lane & (L - 1);
  int g = lane / L;
  int c0 = l * 8;
  int hh = c0 / C;
  int beg = rowptr[n];
  int cnt = rowptr[n + 1] - beg;
  float sdn = sdst[(size_t)n * H + hh];

  // whole-wave coalesced preload of the node's edge list (first 64 edges)
  unsigned ce = 0;
  if (lane < cnt) ce = csr4[beg + lane];

  float a0 = 0.f, a1 = 0.f, a2 = 0.f, a3 = 0.f;
  float a4 = 0.f, a5 = 0.f, a6 = 0.f, a7 = 0.f, ws = 0.f;

  auto body = [&](unsigned p) {
    int s = (int)(p & 0xFFFF);
    float e = ssrc[(size_t)s * H + hh] + sdn;
    e = e > 0.f ? e : 0.2f * e;
    float w = __expf(e);
    uint4 u = *(const uint4*)(h + (size_t)s * HC + c0);
    a0 = fmaf(w, bflo(u.x), a0); a1 = fmaf(w, bfhi(u.x), a1);
    a2 = fmaf(w, bflo(u.y), a2); a3 = fmaf(w, bfhi(u.y), a3);
    a4 = fmaf(w, bflo(u.z), a4); a5 = fmaf(w, bfhi(u.z), a5);
    a6 = fmaf(w, bflo(u.w), a6); a7 = fmaf(w, bfhi(u.w), a7);
    ws += w;
  };

  int T = (cnt + G - 1) / G;  // wave-uniform trip count
  for (int t = 0; t < T; t += 4) {
    int j0 = g + t * G, j1 = j0 + G, j2 = j0 + 2 * G, j3 = j0 + 3 * G;
    // uniform control flow: all lanes execute all shfls with full exec mask
    unsigned p0 = __shfl(ce, j0 & 63, 64);
    unsigned p1 = __shfl(ce, j1 & 63, 64);
    unsigned p2 = __shfl(ce, j2 & 63, 64);
    unsigned p3 = __shfl(ce, j3 & 63, 64);
    if (j0 < cnt) { if (j0 >= 64) p0 = csr4[beg + j0]; body(p0); }
    if (j1 < cnt) { if (j1 >= 64) p1 = csr4[beg + j1]; body(p1); }
    if (j2 < cnt) { if (j2 >= 64) p2 = csr4[beg + j2]; body(p2); }
    if (j3 < cnt) { if (j3 >= 64) p3 = csr4[beg + j3]; body(p3); }
  }

#pragma unroll
  for (int off = L; off < 64; off <<= 1) {
    a0 += __shfl_xor(a0, off, 64); a1 += __shfl_xor(a1, off, 64);
    a2 += __shfl_xor(a2, off, 64); a3 += __shfl_xor(a3, off, 64);
    a4 += __shfl_xor(a4, off, 64); a5 += __shfl_xor(a5, off, 64);
    a6 += __shfl_xor(a6, off, 64); a7 += __shfl_xor(a7, off, 64);
    ws += __shfl_xor(ws, off, 64);
  }
  if (lane < L) {
    float inv = 1.f / ws;  // self-loop guarantees ws > 0
    float4 bA = *(const float4*)(bias + c0);
    float4 bB = *(const float4*)(bias + c0 + 4);
    float v0 = fmaf(a0, inv, bA.x), v1 = fmaf(a1, inv, bA.y);
    float v2 = fmaf(a2, inv, bA.z), v3 = fmaf(a3, inv, bA.w);
    float v4 = fmaf(a4, inv, bB.x), v5 = fmaf(a5, inv, bB.y);
    float v6 = fmaf(a6, inv, bB.z), v7 = fmaf(a7, inv, bB.w);
    if (OUT_BF16) {
      v0 = fmaxf(v0, 0.f); v1 = fmaxf(v1, 0.f);
      v2 = fmaxf(v2, 0.f); v3 = fmaxf(v3, 0.f);
      v4 = fmaxf(v4, 0.f); v5 = fmaxf(v5, 0.f);
      v6 = fmaxf(v6, 0.f); v7 = fmaxf(v7, 0.f);
      uint4 o;
      o.x = (unsigned)f2bf(v0) | ((unsigned)f2bf(v1) << 16);
      o.y = (unsigned)f2bf(v2) | ((unsigned)f2bf(v3) << 16);
      o.z = (unsigned)f2bf(v4) | ((unsigned)f2bf(v5) << 16);
      o.w = (unsigned)f2bf(v6) | ((unsigned)f2bf(v7) << 16);
      ((uint4*)outv)[(size_t)n * (HC / 8) + l] = o;
    } else {
      float* op = (float*)outv + (size_t)n * HC + c0;
      *(float4*)op = make_float4(v0, v1, v2, v3);
      *(float4*)(op + 4) = make_float4(v4, v5, v6, v7);
    }
  }
}

extern "C" void kernel_launch(void* const* d_in, const int* in_sizes, int n_in,
                              void* d_out, int out_size, void* d_ws, size_t ws_size,
                              hipStream_t stream) {
  const float* x   = (const float*)d_in[0];
  const int*   ei  = (const int*)d_in[1];
  const float* W1  = (const float*)d_in[2];
  const float* as1 = (const float*)d_in[3];
  const float* ad1 = (const float*)d_in[4];
  const float* b1  = (const float*)d_in[5];
  const float* W2  = (const float*)d_in[6];
  const float* as2 = (const float*)d_in[7];
  const float* ad2 = (const float*)d_in[8];
  const float* b2  = (const float*)d_in[9];

  const int N = in_sizes[0] / 128;  // 50000
  const int E = in_sizes[1] / 2;    // 800000
  const int ET = E + N;
  const int NBKT = (N + 255) >> 8;              // 196
  const int NBLK = (ET + BCHUNK - 1) / BCHUNK;  // 831
  const int CAP = 6144;                         // per-bucket capacity in bkt2

  char* pc = (char*)d_ws;
  auto alloc = [&](size_t bytes) -> void* {
    void* r = (void*)pc;
    pc += (bytes + 255) & ~(size_t)255;
    return r;
  };
  unsigned short* h1b   = (unsigned short*)alloc((size_t)N * 128 * 2);  // reused as h2b
  unsigned short* out1b = (unsigned short*)alloc((size_t)N * 128 * 2);
  unsigned short* W1t   = (unsigned short*)alloc(128 * 128 * 2);
  unsigned short* W2t   = (unsigned short*)alloc(64 * 128 * 2);
  unsigned short* wsb1  = (unsigned short*)alloc(16 * 128 * 2);
  unsigned short* wsb2  = (unsigned short*)alloc(16 * 128 * 2);
  float* ssrc1 = (float*)alloc((size_t)N * 4 * 4);
  float* sdst1 = (float*)alloc((size_t)N * 4 * 4);
  float* ssrc2 = (float*)alloc((size_t)N * 4);
  float* sdst2 = (float*)alloc((size_t)N * 4);
  int* rowptr = (int*)alloc((size_t)(N + 1) * 4);
  int* cur    = (int*)alloc(256 * 4);
  unsigned* bkt2 = (unsigned*)alloc((size_t)256 * CAP * 4);
  unsigned* csr4 = (unsigned*)alloc((size_t)ET * 4);
  unsigned short* h2b = h1b;  // alias: h1b dead after layer-1 aggregation

  dim3 blk(256);
  const int GB = (N + 63) / 64;  // 782 gemm blocks

  // zero the bucket cursors (workspace arrives poisoned each iteration)
  hipMemsetAsync(cur, 0, 256 * sizeof(int), stream);

  // ---- K1: binned scatter (count+scan+scatter merged) + weight conversion --
  b_scatter_cvt<<<dim3(NBLK + 112), blk, 0, stream>>>(
      ei, E, N, NBLK, CAP, cur, bkt2,
      W1, as1, ad1, W2, as2, ad2, W1t, W2t, wsb1, wsb2);

  // ---- K2: bucket sort || full gemm1 ---------------------------------------
  k_sort_gemm1<<<dim3(NBKT + GB), blk, 0, stream>>>(
      bkt2, CAP, cur, csr4, rowptr, N, ET, NBKT,
      x, W1t, wsb1, h1b, ssrc1, sdst1);

  // ---- layer 1 aggregation: 4 heads x 32, concat, +bias, ReLU --------------
  gat_aggr4<4, 32, 16, 1><<<dim3((N + 3) / 4), blk, 0, stream>>>(
      rowptr, csr4, ssrc1, sdst1, h1b, b1, out1b, N);

  // ---- layer 2: 128 -> 1 head x 64, +bias (scores fused) ----
  gemm_mfma<0, 1><<<dim3(GB), blk, 0, stream>>>(
      out1b, W2t, wsb2, h2b, ssrc2, sdst2, N, 64);
  gat_aggr4<1, 64, 8, 0><<<dim3((N + 3) / 4), blk, 0, stream>>>(
      rowptr, csr4, ssrc2, sdst2, h2b, b2, d_out, N);
}

// Round 6
// 206.510 us; speedup vs baseline: 1.0037x; 1.0037x over previous
//
#include <hip/hip_runtime.h>
#include <hip/hip_bf16.h>

// ---------------------------------------------------------------------------
// GAT 2-layer forward. N=50000, E=800000 (+N self loops).
// Round 19: fuse gemm2 INTO aggr1 — kill the out1b round-trip. Each block
// owns 16 consecutive nodes (4 waves x 4 nodes sequentially); out1 rows
// (post-ReLU bf16, same rounding as before) staged in LDS (16x136 padded:
// 272B row stride = 16B-aligned, bank offset 4/row -> 2-way max, free);
// after __syncthreads the 4 waves compute the 16x64 h2b tile (one 16-col
// MFMA tile per wave) + score tile (wave 0) from LDS. out1b never touches
// memory; gemm2 dispatch gone. h2b UN-ALIASED from h1b (fused kernel writes
// h2b while other blocks still gather h1b).
// Chain: memset -> scatter+cvt -> sort||gemm1 -> fusedAggr1Gemm2 -> aggr2.
// R18 carried: single-pass binned scatter CSR build. R17: wave-uniform shfl
// edge preload. R14: in-lane softmax weights, fused-score GEMMs, packed 4B
// csr. Assumes N <= 65536.
// ---------------------------------------------------------------------------

typedef __attribute__((ext_vector_type(8))) short bf16x8;
typedef __attribute__((ext_vector_type(4))) float f32x4;

#define BCHUNK 1024

__device__ __forceinline__ unsigned short f2bf(float f) {
  unsigned x = __float_as_uint(f);
  unsigned r = (x + 0x7fffu + ((x >> 16) & 1u)) >> 16;  // RNE
  return (unsigned short)r;
}
__device__ __forceinline__ float bf2f(unsigned short u) {
  return __uint_as_float(((unsigned)u) << 16);
}
__device__ __forceinline__ float bflo(unsigned u) {
  return __uint_as_float(u << 16);
}
__device__ __forceinline__ float bfhi(unsigned u) {
  return __uint_as_float(u & 0xffff0000u);
}

// inclusive 256-scan in LDS; returns inclusive sum at tid.
__device__ __forceinline__ int lds_scan256(int v, int* s) {
  int tid = threadIdx.x;
  s[tid] = v;
  __syncthreads();
  for (int o = 1; o < 256; o <<= 1) {
    int t = (tid >= o) ? s[tid - o] : 0;
    __syncthreads();
    s[tid] += t;
    __syncthreads();
  }
  return s[tid];
}

// ---- K1: single-pass binned scatter + weight conversion --------------------
__global__ __launch_bounds__(256) void b_scatter_cvt(
    const int* __restrict__ ei, int E, int N, int NBLK, int CAP,
    int* __restrict__ cur, unsigned* __restrict__ bkt2,
    const float* __restrict__ W1, const float* __restrict__ as1,
    const float* __restrict__ ad1, const float* __restrict__ W2,
    const float* __restrict__ as2, const float* __restrict__ ad2,
    unsigned short* __restrict__ W1t, unsigned short* __restrict__ W2t,
    unsigned short* __restrict__ wsb1, unsigned short* __restrict__ wsb2) {
  int tid = threadIdx.x;
  if ((int)blockIdx.x >= NBLK) {  // conversion blocks
    int i = ((int)blockIdx.x - NBLK) * 256 + tid;
    if (i < 16384) {                       // W1t
      int k = i >> 7, m = i & 127;
      W1t[m * 128 + k] = f2bf(W1[i]);
    } else if (i < 24576) {                // W2t
      int j = i - 16384;
      int k = j / 64, m = j % 64;
      W2t[m * 128 + k] = f2bf(W2[j]);
    } else if (i < 26624) {                // wsb1
      int j = i - 24576;
      int m = j >> 7, k = j & 127;
      float acc = 0.f;
      if (m < 4) {
        for (int c = 0; c < 32; ++c) acc += W1[k * 128 + m * 32 + c] * as1[m * 32 + c];
      } else if (m < 8) {
        for (int c = 0; c < 32; ++c) acc += W1[k * 128 + (m - 4) * 32 + c] * ad1[(m - 4) * 32 + c];
      }
      wsb1[j] = f2bf(acc);
    } else if (i < 28672) {                // wsb2
      int j = i - 26624;
      int m = j >> 7, k = j & 127;
      float acc = 0.f;
      if (m == 0) {
        for (int c = 0; c < 64; ++c) acc += W2[k * 64 + c] * as2[c];
      } else if (m == 1) {
        for (int c = 0; c < 64; ++c) acc += W2[k * 64 + c] * ad2[c];
      }
      wsb2[j] = f2bf(acc);
    }
    return;
  }
  __shared__ unsigned pk[BCHUNK];
  __shared__ unsigned char bk[BCHUNK];
  __shared__ int h[256];
  __shared__ int lcur[256];
  h[tid] = 0;
  __syncthreads();
  int ET = E + N;
  int base = blockIdx.x * BCHUNK;
  int lim = base + BCHUNK;
  if (lim > ET) lim = ET;
  int i = base + tid * 4;
  if (i + 3 < E && i + 4 <= lim) {
    int4 s4 = *(const int4*)(ei + i);
    int4 d4 = *(const int4*)(ei + E + i);
    int o = i - base;
    pk[o + 0] = (unsigned)s4.x | ((unsigned)(d4.x & 255) << 16);
    bk[o + 0] = (unsigned char)(d4.x >> 8); atomicAdd(&h[d4.x >> 8], 1);
    pk[o + 1] = (unsigned)s4.y | ((unsigned)(d4.y & 255) << 16);
    bk[o + 1] = (unsigned char)(d4.y >> 8); atomicAdd(&h[d4.y >> 8], 1);
    pk[o + 2] = (unsigned)s4.z | ((unsigned)(d4.z & 255) << 16);
    bk[o + 2] = (unsigned char)(d4.z >> 8); atomicAdd(&h[d4.z >> 8], 1);
    pk[o + 3] = (unsigned)s4.w | ((unsigned)(d4.w & 255) << 16);
    bk[o + 3] = (unsigned char)(d4.w >> 8); atomicAdd(&h[d4.w >> 8], 1);
  } else {
    for (int k = 0; k < 4; ++k) {
      int idx = i + k;
      if (idx < lim) {
        int s_, d;
        if (idx < E) { s_ = ei[idx]; d = ei[E + idx]; }
        else { s_ = idx - E; d = s_; }
        int o = idx - base;
        pk[o] = (unsigned)s_ | ((unsigned)(d & 255) << 16);
        bk[o] = (unsigned char)(d >> 8);
        atomicAdd(&h[d >> 8], 1);
      }
    }
  }
  __syncthreads();
  // claim per-bucket sub-range (device-scope atomic on global cursor)
  lcur[tid] = tid * CAP + atomicAdd(&cur[tid], h[tid]);
  __syncthreads();
  int cnt_ = lim - base;
  for (int o = tid; o < cnt_; o += 256) {
    int slot = atomicAdd(&lcur[bk[o]], 1);
    bkt2[slot] = pk[o];
  }
}

// ---- MFMA GEMM + fused scores (device body) --------------------------------
template <int AF32, int SC>
__device__ __forceinline__ void gemm_body(
    const void* __restrict__ Av, const unsigned short* __restrict__ Bt,
    const unsigned short* __restrict__ wsb, unsigned short* __restrict__ C,
    float* __restrict__ ssrc, float* __restrict__ sdst, int M, int row0) {
  const int K = 128;
  int lane = threadIdx.x & 63;
  int r = lane & 15, quad = lane >> 4;

  bf16x8 a[4];
  if (AF32) {
    const float* ap = (const float*)Av + (size_t)(row0 + r) * K + quad * 8;
#pragma unroll
    for (int t = 0; t < 4; ++t) {
      float4 lo = *(const float4*)(ap + t * 32);
      float4 hi = *(const float4*)(ap + t * 32 + 4);
      a[t][0] = (short)f2bf(lo.x); a[t][1] = (short)f2bf(lo.y);
      a[t][2] = (short)f2bf(lo.z); a[t][3] = (short)f2bf(lo.w);
      a[t][4] = (short)f2bf(hi.x); a[t][5] = (short)f2bf(hi.y);
      a[t][6] = (short)f2bf(hi.z); a[t][7] = (short)f2bf(hi.w);
    }
  } else {
    const unsigned short* ap = (const unsigned short*)Av + (size_t)(row0 + r) * K + quad * 8;
#pragma unroll
    for (int t = 0; t < 4; ++t) a[t] = *(const bf16x8*)(ap + t * 32);
  }

  for (int c0 = 0; c0 < M; c0 += 16) {
    f32x4 acc = {0.f, 0.f, 0.f, 0.f};
    const unsigned short* bp = Bt + (size_t)(c0 + r) * K + quad * 8;
#pragma unroll
    for (int t = 0; t < 4; ++t) {
      bf16x8 b = *(const bf16x8*)(bp + t * 32);
      acc = __builtin_amdgcn_mfma_f32_16x16x32_bf16(a[t], b, acc, 0, 0, 0);
    }
    unsigned short* cp = C + (size_t)(row0 + quad * 4) * M + c0 + r;
#pragma unroll
    for (int i = 0; i < 4; ++i) cp[(size_t)i * M] = f2bf(acc[i]);
  }

  // fused score tile: cols are wsb rows (0..SC-1 src, SC..2SC-1 dst)
  {
    f32x4 acc = {0.f, 0.f, 0.f, 0.f};
    const unsigned short* bp = wsb + r * 128 + quad * 8;
#pragma unroll
    for (int t = 0; t < 4; ++t) {
      bf16x8 b = *(const bf16x8*)(bp + t * 32);
      acc = __builtin_amdgcn_mfma_f32_16x16x32_bf16(a[t], b, acc, 0, 0, 0);
    }
    int row = row0 + quad * 4;
    if (r < SC) {
#pragma unroll
      for (int i = 0; i < 4; ++i) ssrc[(size_t)(row + i) * SC + r] = acc[i];
    } else if (r < 2 * SC) {
#pragma unroll
      for (int i = 0; i < 4; ++i) sdst[(size_t)(row + i) * SC + (r - SC)] = acc[i];
    }
  }
}

// ---- K2: bucket sort (from strided bkt2) || gemm1 --------------------------
__global__ __launch_bounds__(256) void k_sort_gemm1(
    const unsigned* __restrict__ bkt2, int CAP, const int* __restrict__ cur,
    unsigned* __restrict__ csr4, int* __restrict__ rowptr, int N, int ET,
    int NBKT,
    const float* __restrict__ x, const unsigned short* __restrict__ W1t,
    const unsigned short* __restrict__ wsb1, unsigned short* __restrict__ h1b,
    float* __restrict__ ssrc1, float* __restrict__ sdst1) {
  if ((int)blockIdx.x >= NBKT) {
    int row0 = ((int)blockIdx.x - NBKT) * 64 + (threadIdx.x >> 6) * 16;
    if (row0 >= N) return;
    gemm_body<1, 4>(x, W1t, wsb1, h1b, ssrc1, sdst1, 128, row0);
    return;
  }
  __shared__ int s[256];
  __shared__ int cnt[256];
  int b = blockIdx.x, tid = threadIdx.x;
  int tot = cur[tid];  // per-bucket totals (buckets >= NBKT stayed 0)
  (void)lds_scan256(tot, s);  // s[i] = inclusive sum -> csr4 bases
  int base = (b == 0) ? 0 : s[b - 1];
  int tb = s[b] - base;
  const unsigned* src = bkt2 + (size_t)b * CAP;
  __syncthreads();
  cnt[tid] = 0;
  __syncthreads();
  for (int k = tid; k < tb; k += 512) {
    unsigned p0 = src[k];
    int k1 = k + 256;
    unsigned p1 = (k1 < tb) ? src[k1] : 0u;
    atomicAdd(&cnt[p0 >> 16], 1);
    if (k1 < tb) atomicAdd(&cnt[p1 >> 16], 1);
  }
  __syncthreads();
  int v = cnt[tid];
  int incl = lds_scan256(v, s);
  int excl = incl - v;
  int node = (b << 8) + tid;
  if (node < N) rowptr[node] = base + excl;
  if (tid == 0 && b == NBKT - 1) rowptr[N] = ET;
  cnt[tid] = base + excl;  // becomes the scatter cursor
  __syncthreads();
  for (int k = tid; k < tb; k += 512) {
    unsigned p0 = src[k];
    int k1 = k + 256;
    unsigned p1 = (k1 < tb) ? src[k1] : 0u;
    int slot0 = atomicAdd(&cnt[p0 >> 16], 1);
    csr4[slot0] = p0;
    if (k1 < tb) {
      int slot1 = atomicAdd(&cnt[p1 >> 16], 1);
      csr4[slot1] = p1;
    }
  }
}

// ---- fused layer-1 aggregation + layer-2 GEMM ------------------------------
// Block = 4 waves = 16 nodes. Wave w aggregates nodes base+w*4..+3 (same
// structure as gat_aggr4<4,32,16,1>), stages post-ReLU bf16 out1 rows in
// LDS; after barrier, wave w computes h2b cols [w*16,w*16+16) for the 16
// rows, wave 0 adds the wsb2 score tile (ssrc2/sdst2).
__global__ __launch_bounds__(256) void gat_aggr1_gemm2(
    const int* __restrict__ rowptr, const unsigned* __restrict__ csr4,
    const float* __restrict__ ssrc, const float* __restrict__ sdst,
    const unsigned short* __restrict__ h, const float* __restrict__ bias,
    const unsigned short* __restrict__ W2t, const unsigned short* __restrict__ wsb2,
    unsigned short* __restrict__ h2b, float* __restrict__ ssrc2,
    float* __restrict__ sdst2, int N) {
  const int HC = 128, L = 16, G = 4;
  __shared__ unsigned short sm[16][136];  // +8 pad: 272B stride, 2-way banks
  int lane = threadIdx.x & 63;
  int wv = threadIdx.x >> 6;
  int base = blockIdx.x * 16;
  int l = lane & (L - 1);
  int g = lane / L;
  int c0 = l * 8;
  int hh = c0 >> 5;  // c0 / 32

  for (int i = 0; i < 4; ++i) {
    int row = wv * 4 + i;
    int n = base + row;
    if (n < N) {
      int beg = rowptr[n];
      int cnt = rowptr[n + 1] - beg;
      float sdn = sdst[(size_t)n * 4 + hh];
      unsigned ce = 0;
      if (lane < cnt) ce = csr4[beg + lane];
      float a0 = 0.f, a1 = 0.f, a2 = 0.f, a3 = 0.f;
      float a4 = 0.f, a5 = 0.f, a6 = 0.f, a7 = 0.f, ws = 0.f;
      auto body = [&](unsigned p) {
        int s = (int)(p & 0xFFFF);
        float e = ssrc[(size_t)s * 4 + hh] + sdn;
        e = e > 0.f ? e : 0.2f * e;
        float w = __expf(e);
        uint4 u = *(const uint4*)(h + (size_t)s * HC + c0);
        a0 = fmaf(w, bflo(u.x), a0); a1 = fmaf(w, bfhi(u.x), a1);
        a2 = fmaf(w, bflo(u.y), a2); a3 = fmaf(w, bfhi(u.y), a3);
        a4 = fmaf(w, bflo(u.z), a4); a5 = fmaf(w, bfhi(u.z), a5);
        a6 = fmaf(w, bflo(u.w), a6); a7 = fmaf(w, bfhi(u.w), a7);
        ws += w;
      };
      int T = (cnt + G - 1) / G;
      for (int t = 0; t < T; t += 4) {
        int j0 = g + t * G, j1 = j0 + G, j2 = j0 + 2 * G, j3 = j0 + 3 * G;
        unsigned p0 = __shfl(ce, j0 & 63, 64);
        unsigned p1 = __shfl(ce, j1 & 63, 64);
        unsigned p2 = __shfl(ce, j2 & 63, 64);
        unsigned p3 = __shfl(ce, j3 & 63, 64);
        if (j0 < cnt) { if (j0 >= 64) p0 = csr4[beg + j0]; body(p0); }
        if (j1 < cnt) { if (j1 >= 64) p1 = csr4[beg + j1]; body(p1); }
        if (j2 < cnt) { if (j2 >= 64) p2 = csr4[beg + j2]; body(p2); }
        if (j3 < cnt) { if (j3 >= 64) p3 = csr4[beg + j3]; body(p3); }
      }
#pragma unroll
      for (int off = L; off < 64; off <<= 1) {
        a0 += __shfl_xor(a0, off, 64); a1 += __shfl_xor(a1, off, 64);
        a2 += __shfl_xor(a2, off, 64); a3 += __shfl_xor(a3, off, 64);
        a4 += __shfl_xor(a4, off, 64); a5 += __shfl_xor(a5, off, 64);
        a6 += __shfl_xor(a6, off, 64); a7 += __shfl_xor(a7, off, 64);
        ws += __shfl_xor(ws, off, 64);
      }
      if (lane < L) {
        float inv = 1.f / ws;
        float4 bA = *(const float4*)(bias + c0);
        float4 bB = *(const float4*)(bias + c0 + 4);
        float v0 = fmaxf(fmaf(a0, inv, bA.x), 0.f);
        float v1 = fmaxf(fmaf(a1, inv, bA.y), 0.f);
        float v2 = fmaxf(fmaf(a2, inv, bA.z), 0.f);
        float v3 = fmaxf(fmaf(a3, inv, bA.w), 0.f);
        float v4 = fmaxf(fmaf(a4, inv, bB.x), 0.f);
        float v5 = fmaxf(fmaf(a5, inv, bB.y), 0.f);
        float v6 = fmaxf(fmaf(a6, inv, bB.z), 0.f);
        float v7 = fmaxf(fmaf(a7, inv, bB.w), 0.f);
        uint4 o;
        o.x = (unsigned)f2bf(v0) | ((unsigned)f2bf(v1) << 16);
        o.y = (unsigned)f2bf(v2) | ((unsigned)f2bf(v3) << 16);
        o.z = (unsigned)f2bf(v4) | ((unsigned)f2bf(v5) << 16);
        o.w = (unsigned)f2bf(v6) | ((unsigned)f2bf(v7) << 16);
        *(uint4*)&sm[row][c0] = o;
      }
    } else if (lane < L) {
      *(uint4*)&sm[row][c0] = make_uint4(0, 0, 0, 0);
    }
  }
  __syncthreads();

  // gemm2 from LDS: A = sm rows 0..15 (K=128)
  int r = lane & 15, quad = lane >> 4;
  bf16x8 a[4];
#pragma unroll
  for (int t = 0; t < 4; ++t) a[t] = *(const bf16x8*)&sm[r][quad * 8 + t * 32];
  {
    f32x4 acc = {0.f, 0.f, 0.f, 0.f};
    const unsigned short* bp = W2t + (size_t)(wv * 16 + r) * 128 + quad * 8;
#pragma unroll
    for (int t = 0; t < 4; ++t) {
      bf16x8 b = *(const bf16x8*)(bp + t * 32);
      acc = __builtin_amdgcn_mfma_f32_16x16x32_bf16(a[t], b, acc, 0, 0, 0);
    }
    unsigned short* cp = h2b + (size_t)(base + quad * 4) * 64 + wv * 16 + r;
#pragma unroll
    for (int i = 0; i < 4; ++i)
      if (base + quad * 4 + i < N) cp[(size_t)i * 64] = f2bf(acc[i]);
  }
  if (wv == 0) {
    f32x4 acc = {0.f, 0.f, 0.f, 0.f};
    const unsigned short* bp = wsb2 + r * 128 + quad * 8;
#pragma unroll
    for (int t = 0; t < 4; ++t) {
      bf16x8 b = *(const bf16x8*)(bp + t * 32);
      acc = __builtin_amdgcn_mfma_f32_16x16x32_bf16(a[t], b, acc, 0, 0, 0);
    }
    int row = base + quad * 4;
    if (r == 0) {
#pragma unroll
      for (int i = 0; i < 4; ++i) if (row + i < N) ssrc2[row + i] = acc[i];
    } else if (r == 1) {
#pragma unroll
      for (int i = 0; i < 4; ++i) if (row + i < N) sdst2[row + i] = acc[i];
    }
  }
}

// ---- layer-2 aggregator (unchanged structure) ------------------------------
template <int H, int C, int L, int OUT_BF16>
__global__ __launch_bounds__(256) void gat_aggr4(
    const int* __restrict__ rowptr, const unsigned* __restrict__ csr4,
    const float* __restrict__ ssrc, const float* __restrict__ sdst,
    const unsigned short* __restrict__ h, const float* __restrict__ bias,
    void* __restrict__ outv, int N) {
  const int HC = H * C;  // = 8*L
  const int G = 64 / L;
  int lane = threadIdx.x & 63;
  int n = blockIdx.x * 4 + (threadIdx.x >> 6);
  if (n >= N) return;
  int l = lane & (L - 1);
  int g = lane / L;
  int c0 = l * 8;
  int hh = c0 / C;
  int beg = rowptr[n];
  int cnt = rowptr[n + 1] - beg;
  float sdn = sdst[(size_t)n * H + hh];

  unsigned ce = 0;
  if (lane < cnt) ce = csr4[beg + lane];

  float a0 = 0.f, a1 = 0.f, a2 = 0.f, a3 = 0.f;
  float a4 = 0.f, a5 = 0.f, a6 = 0.f, a7 = 0.f, ws = 0.f;

  auto body = [&](unsigned p) {
    int s = (int)(p & 0xFFFF);
    float e = ssrc[(size_t)s * H + hh] + sdn;
    e = e > 0.f ? e : 0.2f * e;
    float w = __expf(e);
    uint4 u = *(const uint4*)(h + (size_t)s * HC + c0);
    a0 = fmaf(w, bflo(u.x), a0); a1 = fmaf(w, bfhi(u.x), a1);
    a2 = fmaf(w, bflo(u.y), a2); a3 = fmaf(w, bfhi(u.y), a3);
    a4 = fmaf(w, bflo(u.z), a4); a5 = fmaf(w, bfhi(u.z), a5);
    a6 = fmaf(w, bflo(u.w), a6); a7 = fmaf(w, bfhi(u.w), a7);
    ws += w;
  };

  int T = (cnt + G - 1) / G;
  for (int t = 0; t < T; t += 4) {
    int j0 = g + t * G, j1 = j0 + G, j2 = j0 + 2 * G, j3 = j0 + 3 * G;
    unsigned p0 = __shfl(ce, j0 & 63, 64);
    unsigned p1 = __shfl(ce, j1 & 63, 64);
    unsigned p2 = __shfl(ce, j2 & 63, 64);
    unsigned p3 = __shfl(ce, j3 & 63, 64);
    if (j0 < cnt) { if (j0 >= 64) p0 = csr4[beg + j0]; body(p0); }
    if (j1 < cnt) { if (j1 >= 64) p1 = csr4[beg + j1]; body(p1); }
    if (j2 < cnt) { if (j2 >= 64) p2 = csr4[beg + j2]; body(p2); }
    if (j3 < cnt) { if (j3 >= 64) p3 = csr4[beg + j3]; body(p3); }
  }

#pragma unroll
  for (int off = L; off < 64; off <<= 1) {
    a0 += __shfl_xor(a0, off, 64); a1 += __shfl_xor(a1, off, 64);
    a2 += __shfl_xor(a2, off, 64); a3 += __shfl_xor(a3, off, 64);
    a4 += __shfl_xor(a4, off, 64); a5 += __shfl_xor(a5, off, 64);
    a6 += __shfl_xor(a6, off, 64); a7 += __shfl_xor(a7, off, 64);
    ws += __shfl_xor(ws, off, 64);
  }
  if (lane < L) {
    float inv = 1.f / ws;  // self-loop guarantees ws > 0
    float4 bA = *(const float4*)(bias + c0);
    float4 bB = *(const float4*)(bias + c0 + 4);
    float v0 = fmaf(a0, inv, bA.x), v1 = fmaf(a1, inv, bA.y);
    float v2 = fmaf(a2, inv, bA.z), v3 = fmaf(a3, inv, bA.w);
    float v4 = fmaf(a4, inv, bB.x), v5 = fmaf(a5, inv, bB.y);
    float v6 = fmaf(a6, inv, bB.z), v7 = fmaf(a7, inv, bB.w);
    if (OUT_BF16) {
      v0 = fmaxf(v0, 0.f); v1 = fmaxf(v1, 0.f);
      v2 = fmaxf(v2, 0.f); v3 = fmaxf(v3, 0.f);
      v4 = fmaxf(v4, 0.f); v5 = fmaxf(v5, 0.f);
      v6 = fmaxf(v6, 0.f); v7 = fmaxf(v7, 0.f);
      uint4 o;
      o.x = (unsigned)f2bf(v0) | ((unsigned)f2bf(v1) << 16);
      o.y = (unsigned)f2bf(v2) | ((unsigned)f2bf(v3) << 16);
      o.z = (unsigned)f2bf(v4) | ((unsigned)f2bf(v5) << 16);
      o.w = (unsigned)f2bf(v6) | ((unsigned)f2bf(v7) << 16);
      ((uint4*)outv)[(size_t)n * (HC / 8) + l] = o;
    } else {
      float* op = (float*)outv + (size_t)n * HC + c0;
      *(float4*)op = make_float4(v0, v1, v2, v3);
      *(float4*)(op + 4) = make_float4(v4, v5, v6, v7);
    }
  }
}

extern "C" void kernel_launch(void* const* d_in, const int* in_sizes, int n_in,
                              void* d_out, int out_size, void* d_ws, size_t ws_size,
                              hipStream_t stream) {
  const float* x   = (const float*)d_in[0];
  const int*   ei  = (const int*)d_in[1];
  const float* W1  = (const float*)d_in[2];
  const float* as1 = (const float*)d_in[3];
  const float* ad1 = (const float*)d_in[4];
  const float* b1  = (const float*)d_in[5];
  const float* W2  = (const float*)d_in[6];
  const float* as2 = (const float*)d_in[7];
  const float* ad2 = (const float*)d_in[8];
  const float* b2  = (const float*)d_in[9];

  const int N = in_sizes[0] / 128;  // 50000
  const int E = in_sizes[1] / 2;    // 800000
  const int ET = E + N;
  const int NBKT = (N + 255) >> 8;              // 196
  const int NBLK = (ET + BCHUNK - 1) / BCHUNK;  // 831
  const int CAP = 6144;                         // per-bucket capacity in bkt2

  char* pc = (char*)d_ws;
  auto alloc = [&](size_t bytes) -> void* {
    void* r = (void*)pc;
    pc += (bytes + 255) & ~(size_t)255;
    return r;
  };
  unsigned short* h1b   = (unsigned short*)alloc((size_t)N * 128 * 2);
  unsigned short* h2b   = (unsigned short*)alloc((size_t)N * 64 * 2);  // un-aliased!
  unsigned short* W1t   = (unsigned short*)alloc(128 * 128 * 2);
  unsigned short* W2t   = (unsigned short*)alloc(64 * 128 * 2);
  unsigned short* wsb1  = (unsigned short*)alloc(16 * 128 * 2);
  unsigned short* wsb2  = (unsigned short*)alloc(16 * 128 * 2);
  float* ssrc1 = (float*)alloc((size_t)N * 4 * 4);
  float* sdst1 = (float*)alloc((size_t)N * 4 * 4);
  float* ssrc2 = (float*)alloc((size_t)N * 4);
  float* sdst2 = (float*)alloc((size_t)N * 4);
  int* rowptr = (int*)alloc((size_t)(N + 1) * 4);
  int* cur    = (int*)alloc(256 * 4);
  unsigned* bkt2 = (unsigned*)alloc((size_t)256 * CAP * 4);
  unsigned* csr4 = (unsigned*)alloc((size_t)ET * 4);

  dim3 blk(256);
  const int GB = (N + 63) / 64;  // 782 gemm blocks

  // zero the bucket cursors (workspace arrives poisoned each iteration)
  hipMemsetAsync(cur, 0, 256 * sizeof(int), stream);

  // ---- K1: binned scatter (count+scan+scatter merged) + weight conversion --
  b_scatter_cvt<<<dim3(NBLK + 112), blk, 0, stream>>>(
      ei, E, N, NBLK, CAP, cur, bkt2,
      W1, as1, ad1, W2, as2, ad2, W1t, W2t, wsb1, wsb2);

  // ---- K2: bucket sort || full gemm1 ---------------------------------------
  k_sort_gemm1<<<dim3(NBKT + GB), blk, 0, stream>>>(
      bkt2, CAP, cur, csr4, rowptr, N, ET, NBKT,
      x, W1t, wsb1, h1b, ssrc1, sdst1);

  // ---- fused: layer-1 aggregation + gemm2 (+scores2) -----------------------
  gat_aggr1_gemm2<<<dim3((N + 15) / 16), blk, 0, stream>>>(
      rowptr, csr4, ssrc1, sdst1, h1b, b1, W2t, wsb2, h2b, ssrc2, sdst2, N);

  // ---- layer 2 aggregation: 1 head x 64, +bias (f32 out) -------------------
  gat_aggr4<1, 64, 8, 0><<<dim3((N + 3) / 4), blk, 0, stream>>>(
      rowptr, csr4, ssrc2, sdst2, h2b, b2, d_out, N);
}

// Round 7
// 201.587 us; speedup vs baseline: 1.0282x; 1.0244x over previous
//
#include <hip/hip_runtime.h>
#include <hip/hip_bf16.h>

// ---------------------------------------------------------------------------
// GAT 2-layer forward. N=50000, E=800000 (+N self loops).
// Round 20: fix R19's concurrency regression. R19 fused gemm2 into aggr1 but
// gave each wave 4 nodes SEQUENTIALLY -> 12500 waves (was 50000) -> latency-
// bound (PMC: 24% HBM, 35% VALU, 0.7% MFMA, occ 43%). This round: fused
// block = 1024 threads = 16 waves, ONE node per wave (R17 structure), LDS
// stage 16 rows, barrier, waves 0-3 compute the 16x64 h2b MFMA tile, wave 4
// the wsb2 score tile. 50000 waves restored; 2 blocks/CU (32 waves) cap.
// Chain: memset -> scatter+cvt -> sort||gemm1 -> fusedAggr1Gemm2 -> aggr2.
// R18: single-pass binned scatter CSR. R17: wave-uniform shfl edge preload.
// R14: in-lane softmax weights, fused-score GEMMs. Assumes N <= 65536.
// ---------------------------------------------------------------------------

typedef __attribute__((ext_vector_type(8))) short bf16x8;
typedef __attribute__((ext_vector_type(4))) float f32x4;

#define BCHUNK 1024

__device__ __forceinline__ unsigned short f2bf(float f) {
  unsigned x = __float_as_uint(f);
  unsigned r = (x + 0x7fffu + ((x >> 16) & 1u)) >> 16;  // RNE
  return (unsigned short)r;
}
__device__ __forceinline__ float bf2f(unsigned short u) {
  return __uint_as_float(((unsigned)u) << 16);
}
__device__ __forceinline__ float bflo(unsigned u) {
  return __uint_as_float(u << 16);
}
__device__ __forceinline__ float bfhi(unsigned u) {
  return __uint_as_float(u & 0xffff0000u);
}

// inclusive 256-scan in LDS; returns inclusive sum at tid.
__device__ __forceinline__ int lds_scan256(int v, int* s) {
  int tid = threadIdx.x;
  s[tid] = v;
  __syncthreads();
  for (int o = 1; o < 256; o <<= 1) {
    int t = (tid >= o) ? s[tid - o] : 0;
    __syncthreads();
    s[tid] += t;
    __syncthreads();
  }
  return s[tid];
}

// ---- K1: single-pass binned scatter + weight conversion --------------------
__global__ __launch_bounds__(256) void b_scatter_cvt(
    const int* __restrict__ ei, int E, int N, int NBLK, int CAP,
    int* __restrict__ cur, unsigned* __restrict__ bkt2,
    const float* __restrict__ W1, const float* __restrict__ as1,
    const float* __restrict__ ad1, const float* __restrict__ W2,
    const float* __restrict__ as2, const float* __restrict__ ad2,
    unsigned short* __restrict__ W1t, unsigned short* __restrict__ W2t,
    unsigned short* __restrict__ wsb1, unsigned short* __restrict__ wsb2) {
  int tid = threadIdx.x;
  if ((int)blockIdx.x >= NBLK) {  // conversion blocks
    int i = ((int)blockIdx.x - NBLK) * 256 + tid;
    if (i < 16384) {                       // W1t
      int k = i >> 7, m = i & 127;
      W1t[m * 128 + k] = f2bf(W1[i]);
    } else if (i < 24576) {                // W2t
      int j = i - 16384;
      int k = j / 64, m = j % 64;
      W2t[m * 128 + k] = f2bf(W2[j]);
    } else if (i < 26624) {                // wsb1
      int j = i - 24576;
      int m = j >> 7, k = j & 127;
      float acc = 0.f;
      if (m < 4) {
        for (int c = 0; c < 32; ++c) acc += W1[k * 128 + m * 32 + c] * as1[m * 32 + c];
      } else if (m < 8) {
        for (int c = 0; c < 32; ++c) acc += W1[k * 128 + (m - 4) * 32 + c] * ad1[(m - 4) * 32 + c];
      }
      wsb1[j] = f2bf(acc);
    } else if (i < 28672) {                // wsb2
      int j = i - 26624;
      int m = j >> 7, k = j & 127;
      float acc = 0.f;
      if (m == 0) {
        for (int c = 0; c < 64; ++c) acc += W2[k * 64 + c] * as2[c];
      } else if (m == 1) {
        for (int c = 0; c < 64; ++c) acc += W2[k * 64 + c] * ad2[c];
      }
      wsb2[j] = f2bf(acc);
    }
    return;
  }
  __shared__ unsigned pk[BCHUNK];
  __shared__ unsigned char bk[BCHUNK];
  __shared__ int h[256];
  __shared__ int lcur[256];
  h[tid] = 0;
  __syncthreads();
  int ET = E + N;
  int base = blockIdx.x * BCHUNK;
  int lim = base + BCHUNK;
  if (lim > ET) lim = ET;
  int i = base + tid * 4;
  if (i + 3 < E && i + 4 <= lim) {
    int4 s4 = *(const int4*)(ei + i);
    int4 d4 = *(const int4*)(ei + E + i);
    int o = i - base;
    pk[o + 0] = (unsigned)s4.x | ((unsigned)(d4.x & 255) << 16);
    bk[o + 0] = (unsigned char)(d4.x >> 8); atomicAdd(&h[d4.x >> 8], 1);
    pk[o + 1] = (unsigned)s4.y | ((unsigned)(d4.y & 255) << 16);
    bk[o + 1] = (unsigned char)(d4.y >> 8); atomicAdd(&h[d4.y >> 8], 1);
    pk[o + 2] = (unsigned)s4.z | ((unsigned)(d4.z & 255) << 16);
    bk[o + 2] = (unsigned char)(d4.z >> 8); atomicAdd(&h[d4.z >> 8], 1);
    pk[o + 3] = (unsigned)s4.w | ((unsigned)(d4.w & 255) << 16);
    bk[o + 3] = (unsigned char)(d4.w >> 8); atomicAdd(&h[d4.w >> 8], 1);
  } else {
    for (int k = 0; k < 4; ++k) {
      int idx = i + k;
      if (idx < lim) {
        int s_, d;
        if (idx < E) { s_ = ei[idx]; d = ei[E + idx]; }
        else { s_ = idx - E; d = s_; }
        int o = idx - base;
        pk[o] = (unsigned)s_ | ((unsigned)(d & 255) << 16);
        bk[o] = (unsigned char)(d >> 8);
        atomicAdd(&h[d >> 8], 1);
      }
    }
  }
  __syncthreads();
  // claim per-bucket sub-range (device-scope atomic on global cursor)
  lcur[tid] = tid * CAP + atomicAdd(&cur[tid], h[tid]);
  __syncthreads();
  int cnt_ = lim - base;
  for (int o = tid; o < cnt_; o += 256) {
    int slot = atomicAdd(&lcur[bk[o]], 1);
    bkt2[slot] = pk[o];
  }
}

// ---- MFMA GEMM + fused scores (device body) --------------------------------
template <int AF32, int SC>
__device__ __forceinline__ void gemm_body(
    const void* __restrict__ Av, const unsigned short* __restrict__ Bt,
    const unsigned short* __restrict__ wsb, unsigned short* __restrict__ C,
    float* __restrict__ ssrc, float* __restrict__ sdst, int M, int row0) {
  const int K = 128;
  int lane = threadIdx.x & 63;
  int r = lane & 15, quad = lane >> 4;

  bf16x8 a[4];
  if (AF32) {
    const float* ap = (const float*)Av + (size_t)(row0 + r) * K + quad * 8;
#pragma unroll
    for (int t = 0; t < 4; ++t) {
      float4 lo = *(const float4*)(ap + t * 32);
      float4 hi = *(const float4*)(ap + t * 32 + 4);
      a[t][0] = (short)f2bf(lo.x); a[t][1] = (short)f2bf(lo.y);
      a[t][2] = (short)f2bf(lo.z); a[t][3] = (short)f2bf(lo.w);
      a[t][4] = (short)f2bf(hi.x); a[t][5] = (short)f2bf(hi.y);
      a[t][6] = (short)f2bf(hi.z); a[t][7] = (short)f2bf(hi.w);
    }
  } else {
    const unsigned short* ap = (const unsigned short*)Av + (size_t)(row0 + r) * K + quad * 8;
#pragma unroll
    for (int t = 0; t < 4; ++t) a[t] = *(const bf16x8*)(ap + t * 32);
  }

  for (int c0 = 0; c0 < M; c0 += 16) {
    f32x4 acc = {0.f, 0.f, 0.f, 0.f};
    const unsigned short* bp = Bt + (size_t)(c0 + r) * K + quad * 8;
#pragma unroll
    for (int t = 0; t < 4; ++t) {
      bf16x8 b = *(const bf16x8*)(bp + t * 32);
      acc = __builtin_amdgcn_mfma_f32_16x16x32_bf16(a[t], b, acc, 0, 0, 0);
    }
    unsigned short* cp = C + (size_t)(row0 + quad * 4) * M + c0 + r;
#pragma unroll
    for (int i = 0; i < 4; ++i) cp[(size_t)i * M] = f2bf(acc[i]);
  }

  // fused score tile: cols are wsb rows (0..SC-1 src, SC..2SC-1 dst)
  {
    f32x4 acc = {0.f, 0.f, 0.f, 0.f};
    const unsigned short* bp = wsb + r * 128 + quad * 8;
#pragma unroll
    for (int t = 0; t < 4; ++t) {
      bf16x8 b = *(const bf16x8*)(bp + t * 32);
      acc = __builtin_amdgcn_mfma_f32_16x16x32_bf16(a[t], b, acc, 0, 0, 0);
    }
    int row = row0 + quad * 4;
    if (r < SC) {
#pragma unroll
      for (int i = 0; i < 4; ++i) ssrc[(size_t)(row + i) * SC + r] = acc[i];
    } else if (r < 2 * SC) {
#pragma unroll
      for (int i = 0; i < 4; ++i) sdst[(size_t)(row + i) * SC + (r - SC)] = acc[i];
    }
  }
}

// ---- K2: bucket sort (from strided bkt2) || gemm1 --------------------------
__global__ __launch_bounds__(256) void k_sort_gemm1(
    const unsigned* __restrict__ bkt2, int CAP, const int* __restrict__ cur,
    unsigned* __restrict__ csr4, int* __restrict__ rowptr, int N, int ET,
    int NBKT,
    const float* __restrict__ x, const unsigned short* __restrict__ W1t,
    const unsigned short* __restrict__ wsb1, unsigned short* __restrict__ h1b,
    float* __restrict__ ssrc1, float* __restrict__ sdst1) {
  if ((int)blockIdx.x >= NBKT) {
    int row0 = ((int)blockIdx.x - NBKT) * 64 + (threadIdx.x >> 6) * 16;
    if (row0 >= N) return;
    gemm_body<1, 4>(x, W1t, wsb1, h1b, ssrc1, sdst1, 128, row0);
    return;
  }
  __shared__ int s[256];
  __shared__ int cnt[256];
  int b = blockIdx.x, tid = threadIdx.x;
  int tot = cur[tid];  // per-bucket totals (buckets >= NBKT stayed 0)
  (void)lds_scan256(tot, s);  // s[i] = inclusive sum -> csr4 bases
  int base = (b == 0) ? 0 : s[b - 1];
  int tb = s[b] - base;
  const unsigned* src = bkt2 + (size_t)b * CAP;
  __syncthreads();
  cnt[tid] = 0;
  __syncthreads();
  for (int k = tid; k < tb; k += 512) {
    unsigned p0 = src[k];
    int k1 = k + 256;
    unsigned p1 = (k1 < tb) ? src[k1] : 0u;
    atomicAdd(&cnt[p0 >> 16], 1);
    if (k1 < tb) atomicAdd(&cnt[p1 >> 16], 1);
  }
  __syncthreads();
  int v = cnt[tid];
  int incl = lds_scan256(v, s);
  int excl = incl - v;
  int node = (b << 8) + tid;
  if (node < N) rowptr[node] = base + excl;
  if (tid == 0 && b == NBKT - 1) rowptr[N] = ET;
  cnt[tid] = base + excl;  // becomes the scatter cursor
  __syncthreads();
  for (int k = tid; k < tb; k += 512) {
    unsigned p0 = src[k];
    int k1 = k + 256;
    unsigned p1 = (k1 < tb) ? src[k1] : 0u;
    int slot0 = atomicAdd(&cnt[p0 >> 16], 1);
    csr4[slot0] = p0;
    if (k1 < tb) {
      int slot1 = atomicAdd(&cnt[p1 >> 16], 1);
      csr4[slot1] = p1;
    }
  }
}

// ---- fused layer-1 aggregation + layer-2 GEMM (1024 threads) ---------------
// Block = 16 waves = 16 nodes, ONE node per wave (full TLP: 50000 waves).
// Each wave aggregates its node (L=16 lanes/edge, G=4 groups, shfl preload),
// writes its post-ReLU bf16 out1 row to LDS. After the barrier, waves 0-3
// compute the 16x64 h2b MFMA tile (16 cols each); wave 4 the wsb2 score tile.
__global__ __launch_bounds__(1024) void gat_aggr1_gemm2(
    const int* __restrict__ rowptr, const unsigned* __restrict__ csr4,
    const float* __restrict__ ssrc, const float* __restrict__ sdst,
    const unsigned short* __restrict__ h, const float* __restrict__ bias,
    const unsigned short* __restrict__ W2t, const unsigned short* __restrict__ wsb2,
    unsigned short* __restrict__ h2b, float* __restrict__ ssrc2,
    float* __restrict__ sdst2, int N) {
  const int HC = 128, L = 16, G = 4;
  __shared__ unsigned short sm[16][136];  // +8 pad: 272B stride, 2-way banks
  int lane = threadIdx.x & 63;
  int wv = threadIdx.x >> 6;  // 0..15
  int base = blockIdx.x * 16;
  int l = lane & (L - 1);
  int g = lane / L;
  int c0 = l * 8;
  int hh = c0 >> 5;  // c0 / 32
  int n = base + wv;

  if (n < N) {
    int beg = rowptr[n];
    int cnt = rowptr[n + 1] - beg;
    float sdn = sdst[(size_t)n * 4 + hh];
    unsigned ce = 0;
    if (lane < cnt) ce = csr4[beg + lane];
    float a0 = 0.f, a1 = 0.f, a2 = 0.f, a3 = 0.f;
    float a4 = 0.f, a5 = 0.f, a6 = 0.f, a7 = 0.f, ws = 0.f;
    auto body = [&](unsigned p) {
      int s = (int)(p & 0xFFFF);
      float e = ssrc[(size_t)s * 4 + hh] + sdn;
      e = e > 0.f ? e : 0.2f * e;
      float w = __expf(e);
      uint4 u = *(const uint4*)(h + (size_t)s * HC + c0);
      a0 = fmaf(w, bflo(u.x), a0); a1 = fmaf(w, bfhi(u.x), a1);
      a2 = fmaf(w, bflo(u.y), a2); a3 = fmaf(w, bfhi(u.y), a3);
      a4 = fmaf(w, bflo(u.z), a4); a5 = fmaf(w, bfhi(u.z), a5);
      a6 = fmaf(w, bflo(u.w), a6); a7 = fmaf(w, bfhi(u.w), a7);
      ws += w;
    };
    int T = (cnt + G - 1) / G;  // wave-uniform trip count
    for (int t = 0; t < T; t += 4) {
      int j0 = g + t * G, j1 = j0 + G, j2 = j0 + 2 * G, j3 = j0 + 3 * G;
      unsigned p0 = __shfl(ce, j0 & 63, 64);
      unsigned p1 = __shfl(ce, j1 & 63, 64);
      unsigned p2 = __shfl(ce, j2 & 63, 64);
      unsigned p3 = __shfl(ce, j3 & 63, 64);
      if (j0 < cnt) { if (j0 >= 64) p0 = csr4[beg + j0]; body(p0); }
      if (j1 < cnt) { if (j1 >= 64) p1 = csr4[beg + j1]; body(p1); }
      if (j2 < cnt) { if (j2 >= 64) p2 = csr4[beg + j2]; body(p2); }
      if (j3 < cnt) { if (j3 >= 64) p3 = csr4[beg + j3]; body(p3); }
    }
#pragma unroll
    for (int off = L; off < 64; off <<= 1) {
      a0 += __shfl_xor(a0, off, 64); a1 += __shfl_xor(a1, off, 64);
      a2 += __shfl_xor(a2, off, 64); a3 += __shfl_xor(a3, off, 64);
      a4 += __shfl_xor(a4, off, 64); a5 += __shfl_xor(a5, off, 64);
      a6 += __shfl_xor(a6, off, 64); a7 += __shfl_xor(a7, off, 64);
      ws += __shfl_xor(ws, off, 64);
    }
    if (lane < L) {
      float inv = 1.f / ws;
      float4 bA = *(const float4*)(bias + c0);
      float4 bB = *(const float4*)(bias + c0 + 4);
      float v0 = fmaxf(fmaf(a0, inv, bA.x), 0.f);
      float v1 = fmaxf(fmaf(a1, inv, bA.y), 0.f);
      float v2 = fmaxf(fmaf(a2, inv, bA.z), 0.f);
      float v3 = fmaxf(fmaf(a3, inv, bA.w), 0.f);
      float v4 = fmaxf(fmaf(a4, inv, bB.x), 0.f);
      float v5 = fmaxf(fmaf(a5, inv, bB.y), 0.f);
      float v6 = fmaxf(fmaf(a6, inv, bB.z), 0.f);
      float v7 = fmaxf(fmaf(a7, inv, bB.w), 0.f);
      uint4 o;
      o.x = (unsigned)f2bf(v0) | ((unsigned)f2bf(v1) << 16);
      o.y = (unsigned)f2bf(v2) | ((unsigned)f2bf(v3) << 16);
      o.z = (unsigned)f2bf(v4) | ((unsigned)f2bf(v5) << 16);
      o.w = (unsigned)f2bf(v6) | ((unsigned)f2bf(v7) << 16);
      *(uint4*)&sm[wv][c0] = o;
    }
  } else if (lane < L) {
    *(uint4*)&sm[wv][c0] = make_uint4(0, 0, 0, 0);
  }
  __syncthreads();

  if (wv >= 5) return;
  // gemm2 from LDS: A = sm rows 0..15 (K=128)
  int r = lane & 15, quad = lane >> 4;
  bf16x8 a[4];
#pragma unroll
  for (int t = 0; t < 4; ++t) a[t] = *(const bf16x8*)&sm[r][quad * 8 + t * 32];
  if (wv < 4) {
    f32x4 acc = {0.f, 0.f, 0.f, 0.f};
    const unsigned short* bp = W2t + (size_t)(wv * 16 + r) * 128 + quad * 8;
#pragma unroll
    for (int t = 0; t < 4; ++t) {
      bf16x8 b = *(const bf16x8*)(bp + t * 32);
      acc = __builtin_amdgcn_mfma_f32_16x16x32_bf16(a[t], b, acc, 0, 0, 0);
    }
    unsigned short* cp = h2b + (size_t)(base + quad * 4) * 64 + wv * 16 + r;
#pragma unroll
    for (int i = 0; i < 4; ++i)
      if (base + quad * 4 + i < N) cp[(size_t)i * 64] = f2bf(acc[i]);
  } else {  // wv == 4: score tile
    f32x4 acc = {0.f, 0.f, 0.f, 0.f};
    const unsigned short* bp = wsb2 + r * 128 + quad * 8;
#pragma unroll
    for (int t = 0; t < 4; ++t) {
      bf16x8 b = *(const bf16x8*)(bp + t * 32);
      acc = __builtin_amdgcn_mfma_f32_16x16x32_bf16(a[t], b, acc, 0, 0, 0);
    }
    int row = base + quad * 4;
    if (r == 0) {
#pragma unroll
      for (int i = 0; i < 4; ++i) if (row + i < N) ssrc2[row + i] = acc[i];
    } else if (r == 1) {
#pragma unroll
      for (int i = 0; i < 4; ++i) if (row + i < N) sdst2[row + i] = acc[i];
    }
  }
}

// ---- layer-2 aggregator (unchanged structure) ------------------------------
template <int H, int C, int L, int OUT_BF16>
__global__ __launch_bounds__(256) void gat_aggr4(
    const int* __restrict__ rowptr, const unsigned* __restrict__ csr4,
    const float* __restrict__ ssrc, const float* __restrict__ sdst,
    const unsigned short* __restrict__ h, const float* __restrict__ bias,
    void* __restrict__ outv, int N) {
  const int HC = H * C;  // = 8*L
  const int G = 64 / L;
  int lane = threadIdx.x & 63;
  int n = blockIdx.x * 4 + (threadIdx.x >> 6);
  if (n >= N) return;
  int l = lane & (L - 1);
  int g = lane / L;
  int c0 = l * 8;
  int hh = c0 / C;
  int beg = rowptr[n];
  int cnt = rowptr[n + 1] - beg;
  float sdn = sdst[(size_t)n * H + hh];

  unsigned ce = 0;
  if (lane < cnt) ce = csr4[beg + lane];

  float a0 = 0.f, a1 = 0.f, a2 = 0.f, a3 = 0.f;
  float a4 = 0.f, a5 = 0.f, a6 = 0.f, a7 = 0.f, ws = 0.f;

  auto body = [&](unsigned p) {
    int s = (int)(p & 0xFFFF);
    float e = ssrc[(size_t)s * H + hh] + sdn;
    e = e > 0.f ? e : 0.2f * e;
    float w = __expf(e);
    uint4 u = *(const uint4*)(h + (size_t)s * HC + c0);
    a0 = fmaf(w, bflo(u.x), a0); a1 = fmaf(w, bfhi(u.x), a1);
    a2 = fmaf(w, bflo(u.y), a2); a3 = fmaf(w, bfhi(u.y), a3);
    a4 = fmaf(w, bflo(u.z), a4); a5 = fmaf(w, bfhi(u.z), a5);
    a6 = fmaf(w, bflo(u.w), a6); a7 = fmaf(w, bfhi(u.w), a7);
    ws += w;
  };

  int T = (cnt + G - 1) / G;
  for (int t = 0; t < T; t += 4) {
    int j0 = g + t * G, j1 = j0 + G, j2 = j0 + 2 * G, j3 = j0 + 3 * G;
    unsigned p0 = __shfl(ce, j0 & 63, 64);
    unsigned p1 = __shfl(ce, j1 & 63, 64);
    unsigned p2 = __shfl(ce, j2 & 63, 64);
    unsigned p3 = __shfl(ce, j3 & 63, 64);
    if (j0 < cnt) { if (j0 >= 64) p0 = csr4[beg + j0]; body(p0); }
    if (j1 < cnt) { if (j1 >= 64) p1 = csr4[beg + j1]; body(p1); }
    if (j2 < cnt) { if (j2 >= 64) p2 = csr4[beg + j2]; body(p2); }
    if (j3 < cnt) { if (j3 >= 64) p3 = csr4[beg + j3]; body(p3); }
  }

#pragma unroll
  for (int off = L; off < 64; off <<= 1) {
    a0 += __shfl_xor(a0, off, 64); a1 += __shfl_xor(a1, off, 64);
    a2 += __shfl_xor(a2, off, 64); a3 += __shfl_xor(a3, off, 64);
    a4 += __shfl_xor(a4, off, 64); a5 += __shfl_xor(a5, off, 64);
    a6 += __shfl_xor(a6, off, 64); a7 += __shfl_xor(a7, off, 64);
    ws += __shfl_xor(ws, off, 64);
  }
  if (lane < L) {
    float inv = 1.f / ws;  // self-loop guarantees ws > 0
    float4 bA = *(const float4*)(bias + c0);
    float4 bB = *(const float4*)(bias + c0 + 4);
    float v0 = fmaf(a0, inv, bA.x), v1 = fmaf(a1, inv, bA.y);
    float v2 = fmaf(a2, inv, bA.z), v3 = fmaf(a3, inv, bA.w);
    float v4 = fmaf(a4, inv, bB.x), v5 = fmaf(a5, inv, bB.y);
    float v6 = fmaf(a6, inv, bB.z), v7 = fmaf(a7, inv, bB.w);
    if (OUT_BF16) {
      v0 = fmaxf(v0, 0.f); v1 = fmaxf(v1, 0.f);
      v2 = fmaxf(v2, 0.f); v3 = fmaxf(v3, 0.f);
      v4 = fmaxf(v4, 0.f); v5 = fmaxf(v5, 0.f);
      v6 = fmaxf(v6, 0.f); v7 = fmaxf(v7, 0.f);
      uint4 o;
      o.x = (unsigned)f2bf(v0) | ((unsigned)f2bf(v1) << 16);
      o.y = (unsigned)f2bf(v2) | ((unsigned)f2bf(v3) << 16);
      o.z = (unsigned)f2bf(v4) | ((unsigned)f2bf(v5) << 16);
      o.w = (unsigned)f2bf(v6) | ((unsigned)f2bf(v7) << 16);
      ((uint4*)outv)[(size_t)n * (HC / 8) + l] = o;
    } else {
      float* op = (float*)outv + (size_t)n * HC + c0;
      *(float4*)op = make_float4(v0, v1, v2, v3);
      *(float4*)(op + 4) = make_float4(v4, v5, v6, v7);
    }
  }
}

extern "C" void kernel_launch(void* const* d_in, const int* in_sizes, int n_in,
                              void* d_out, int out_size, void* d_ws, size_t ws_size,
                              hipStream_t stream) {
  const float* x   = (const float*)d_in[0];
  const int*   ei  = (const int*)d_in[1];
  const float* W1  = (const float*)d_in[2];
  const float* as1 = (const float*)d_in[3];
  const float* ad1 = (const float*)d_in[4];
  const float* b1  = (const float*)d_in[5];
  const float* W2  = (const float*)d_in[6];
  const float* as2 = (const float*)d_in[7];
  const float* ad2 = (const float*)d_in[8];
  const float* b2  = (const float*)d_in[9];

  const int N = in_sizes[0] / 128;  // 50000
  const int E = in_sizes[1] / 2;    // 800000
  const int ET = E + N;
  const int NBKT = (N + 255) >> 8;              // 196
  const int NBLK = (ET + BCHUNK - 1) / BCHUNK;  // 831
  const int CAP = 6144;                         // per-bucket capacity in bkt2

  char* pc = (char*)d_ws;
  auto alloc = [&](size_t bytes) -> void* {
    void* r = (void*)pc;
    pc += (bytes + 255) & ~(size_t)255;
    return r;
  };
  unsigned short* h1b   = (unsigned short*)alloc((size_t)N * 128 * 2);
  unsigned short* h2b   = (unsigned short*)alloc((size_t)N * 64 * 2);  // un-aliased
  unsigned short* W1t   = (unsigned short*)alloc(128 * 128 * 2);
  unsigned short* W2t   = (unsigned short*)alloc(64 * 128 * 2);
  unsigned short* wsb1  = (unsigned short*)alloc(16 * 128 * 2);
  unsigned short* wsb2  = (unsigned short*)alloc(16 * 128 * 2);
  float* ssrc1 = (float*)alloc((size_t)N * 4 * 4);
  float* sdst1 = (float*)alloc((size_t)N * 4 * 4);
  float* ssrc2 = (float*)alloc((size_t)N * 4);
  float* sdst2 = (float*)alloc((size_t)N * 4);
  int* rowptr = (int*)alloc((size_t)(N + 1) * 4);
  int* cur    = (int*)alloc(256 * 4);
  unsigned* bkt2 = (unsigned*)alloc((size_t)256 * CAP * 4);
  unsigned* csr4 = (unsigned*)alloc((size_t)ET * 4);

  dim3 blk(256);
  const int GB = (N + 63) / 64;  // 782 gemm blocks

  // zero the bucket cursors (workspace arrives poisoned each iteration)
  hipMemsetAsync(cur, 0, 256 * sizeof(int), stream);

  // ---- K1: binned scatter (count+scan+scatter merged) + weight conversion --
  b_scatter_cvt<<<dim3(NBLK + 112), blk, 0, stream>>>(
      ei, E, N, NBLK, CAP, cur, bkt2,
      W1, as1, ad1, W2, as2, ad2, W1t, W2t, wsb1, wsb2);

  // ---- K2: bucket sort || full gemm1 ---------------------------------------
  k_sort_gemm1<<<dim3(NBKT + GB), blk, 0, stream>>>(
      bkt2, CAP, cur, csr4, rowptr, N, ET, NBKT,
      x, W1t, wsb1, h1b, ssrc1, sdst1);

  // ---- fused: layer-1 aggregation + gemm2 (+scores2), 1024-thread blocks ---
  gat_aggr1_gemm2<<<dim3((N + 15) / 16), dim3(1024), 0, stream>>>(
      rowptr, csr4, ssrc1, sdst1, h1b, b1, W2t, wsb2, h2b, ssrc2, sdst2, N);

  // ---- layer 2 aggregation: 1 head x 64, +bias (f32 out) -------------------
  gat_aggr4<1, 64, 8, 0><<<dim3((N + 3) / 4), blk, 0, stream>>>(
      rowptr, csr4, ssrc2, sdst2, h2b, b2, d_out, N);
}

// Round 8
// 196.279 us; speedup vs baseline: 1.0560x; 1.0270x over previous
//
#include <hip/hip_runtime.h>
#include <hip/hip_bf16.h>

// ---------------------------------------------------------------------------
// GAT 2-layer forward. N=50000, E=800000 (+N self loops).
// Round 21: software-pipeline the aggregator gathers. PMC on the fused
// kernel (48.6us): 26% HBM / 42% VALU / 56% occ -> ~50% stall, fetch path
// parallelism-limited (Little's law: ~2TB/s = ~150-200 outstanding reqs/CU,
// matching 18 waves x ~8 loads). Fix: preload-then-consume pipeline. Shfl
// D edge packets up front (uniform exec), issue ALL D score + D h-row loads
// back-to-back (D=6 aggr1 covers cnt<=24 ~96%; D=3 aggr2), then consume.
// Wasted slots hit row 0 (hot line, ce=0 default) - no HBM cost; consume
// predicated -> summation order identical (absmax unchanged). Tail (cnt>DG)
// = old wave-uniform shfl loop. __launch_bounds__(1024,8) pins VGPR<=64 so
// 2 blocks/CU survive the pipeline arrays (compile-time indexed).
// R20: fused aggr1+gemm2, 1 node/wave. R18: single-pass binned CSR build.
// R14: in-lane softmax weights, fused-score GEMMs. Assumes N <= 65536.
// ---------------------------------------------------------------------------

typedef __attribute__((ext_vector_type(8))) short bf16x8;
typedef __attribute__((ext_vector_type(4))) float f32x4;

#define BCHUNK 1024

__device__ __forceinline__ unsigned short f2bf(float f) {
  unsigned x = __float_as_uint(f);
  unsigned r = (x + 0x7fffu + ((x >> 16) & 1u)) >> 16;  // RNE
  return (unsigned short)r;
}
__device__ __forceinline__ float bf2f(unsigned short u) {
  return __uint_as_float(((unsigned)u) << 16);
}
__device__ __forceinline__ float bflo(unsigned u) {
  return __uint_as_float(u << 16);
}
__device__ __forceinline__ float bfhi(unsigned u) {
  return __uint_as_float(u & 0xffff0000u);
}

// inclusive 256-scan in LDS; returns inclusive sum at tid.
__device__ __forceinline__ int lds_scan256(int v, int* s) {
  int tid = threadIdx.x;
  s[tid] = v;
  __syncthreads();
  for (int o = 1; o < 256; o <<= 1) {
    int t = (tid >= o) ? s[tid - o] : 0;
    __syncthreads();
    s[tid] += t;
    __syncthreads();
  }
  return s[tid];
}

// ---- K1: single-pass binned scatter + weight conversion --------------------
__global__ __launch_bounds__(256) void b_scatter_cvt(
    const int* __restrict__ ei, int E, int N, int NBLK, int CAP,
    int* __restrict__ cur, unsigned* __restrict__ bkt2,
    const float* __restrict__ W1, const float* __restrict__ as1,
    const float* __restrict__ ad1, const float* __restrict__ W2,
    const float* __restrict__ as2, const float* __restrict__ ad2,
    unsigned short* __restrict__ W1t, unsigned short* __restrict__ W2t,
    unsigned short* __restrict__ wsb1, unsigned short* __restrict__ wsb2) {
  int tid = threadIdx.x;
  if ((int)blockIdx.x >= NBLK) {  // conversion blocks
    int i = ((int)blockIdx.x - NBLK) * 256 + tid;
    if (i < 16384) {                       // W1t
      int k = i >> 7, m = i & 127;
      W1t[m * 128 + k] = f2bf(W1[i]);
    } else if (i < 24576) {                // W2t
      int j = i - 16384;
      int k = j / 64, m = j % 64;
      W2t[m * 128 + k] = f2bf(W2[j]);
    } else if (i < 26624) {                // wsb1
      int j = i - 24576;
      int m = j >> 7, k = j & 127;
      float acc = 0.f;
      if (m < 4) {
        for (int c = 0; c < 32; ++c) acc += W1[k * 128 + m * 32 + c] * as1[m * 32 + c];
      } else if (m < 8) {
        for (int c = 0; c < 32; ++c) acc += W1[k * 128 + (m - 4) * 32 + c] * ad1[(m - 4) * 32 + c];
      }
      wsb1[j] = f2bf(acc);
    } else if (i < 28672) {                // wsb2
      int j = i - 26624;
      int m = j >> 7, k = j & 127;
      float acc = 0.f;
      if (m == 0) {
        for (int c = 0; c < 64; ++c) acc += W2[k * 64 + c] * as2[c];
      } else if (m == 1) {
        for (int c = 0; c < 64; ++c) acc += W2[k * 64 + c] * ad2[c];
      }
      wsb2[j] = f2bf(acc);
    }
    return;
  }
  __shared__ unsigned pk[BCHUNK];
  __shared__ unsigned char bk[BCHUNK];
  __shared__ int h[256];
  __shared__ int lcur[256];
  h[tid] = 0;
  __syncthreads();
  int ET = E + N;
  int base = blockIdx.x * BCHUNK;
  int lim = base + BCHUNK;
  if (lim > ET) lim = ET;
  int i = base + tid * 4;
  if (i + 3 < E && i + 4 <= lim) {
    int4 s4 = *(const int4*)(ei + i);
    int4 d4 = *(const int4*)(ei + E + i);
    int o = i - base;
    pk[o + 0] = (unsigned)s4.x | ((unsigned)(d4.x & 255) << 16);
    bk[o + 0] = (unsigned char)(d4.x >> 8); atomicAdd(&h[d4.x >> 8], 1);
    pk[o + 1] = (unsigned)s4.y | ((unsigned)(d4.y & 255) << 16);
    bk[o + 1] = (unsigned char)(d4.y >> 8); atomicAdd(&h[d4.y >> 8], 1);
    pk[o + 2] = (unsigned)s4.z | ((unsigned)(d4.z & 255) << 16);
    bk[o + 2] = (unsigned char)(d4.z >> 8); atomicAdd(&h[d4.z >> 8], 1);
    pk[o + 3] = (unsigned)s4.w | ((unsigned)(d4.w & 255) << 16);
    bk[o + 3] = (unsigned char)(d4.w >> 8); atomicAdd(&h[d4.w >> 8], 1);
  } else {
    for (int k = 0; k < 4; ++k) {
      int idx = i + k;
      if (idx < lim) {
        int s_, d;
        if (idx < E) { s_ = ei[idx]; d = ei[E + idx]; }
        else { s_ = idx - E; d = s_; }
        int o = idx - base;
        pk[o] = (unsigned)s_ | ((unsigned)(d & 255) << 16);
        bk[o] = (unsigned char)(d >> 8);
        atomicAdd(&h[d >> 8], 1);
      }
    }
  }
  __syncthreads();
  // claim per-bucket sub-range (device-scope atomic on global cursor)
  lcur[tid] = tid * CAP + atomicAdd(&cur[tid], h[tid]);
  __syncthreads();
  int cnt_ = lim - base;
  for (int o = tid; o < cnt_; o += 256) {
    int slot = atomicAdd(&lcur[bk[o]], 1);
    bkt2[slot] = pk[o];
  }
}

// ---- MFMA GEMM + fused scores (device body) --------------------------------
template <int AF32, int SC>
__device__ __forceinline__ void gemm_body(
    const void* __restrict__ Av, const unsigned short* __restrict__ Bt,
    const unsigned short* __restrict__ wsb, unsigned short* __restrict__ C,
    float* __restrict__ ssrc, float* __restrict__ sdst, int M, int row0) {
  const int K = 128;
  int lane = threadIdx.x & 63;
  int r = lane & 15, quad = lane >> 4;

  bf16x8 a[4];
  if (AF32) {
    const float* ap = (const float*)Av + (size_t)(row0 + r) * K + quad * 8;
#pragma unroll
    for (int t = 0; t < 4; ++t) {
      float4 lo = *(const float4*)(ap + t * 32);
      float4 hi = *(const float4*)(ap + t * 32 + 4);
      a[t][0] = (short)f2bf(lo.x); a[t][1] = (short)f2bf(lo.y);
      a[t][2] = (short)f2bf(lo.z); a[t][3] = (short)f2bf(lo.w);
      a[t][4] = (short)f2bf(hi.x); a[t][5] = (short)f2bf(hi.y);
      a[t][6] = (short)f2bf(hi.z); a[t][7] = (short)f2bf(hi.w);
    }
  } else {
    const unsigned short* ap = (const unsigned short*)Av + (size_t)(row0 + r) * K + quad * 8;
#pragma unroll
    for (int t = 0; t < 4; ++t) a[t] = *(const bf16x8*)(ap + t * 32);
  }

  for (int c0 = 0; c0 < M; c0 += 16) {
    f32x4 acc = {0.f, 0.f, 0.f, 0.f};
    const unsigned short* bp = Bt + (size_t)(c0 + r) * K + quad * 8;
#pragma unroll
    for (int t = 0; t < 4; ++t) {
      bf16x8 b = *(const bf16x8*)(bp + t * 32);
      acc = __builtin_amdgcn_mfma_f32_16x16x32_bf16(a[t], b, acc, 0, 0, 0);
    }
    unsigned short* cp = C + (size_t)(row0 + quad * 4) * M + c0 + r;
#pragma unroll
    for (int i = 0; i < 4; ++i) cp[(size_t)i * M] = f2bf(acc[i]);
  }

  // fused score tile: cols are wsb rows (0..SC-1 src, SC..2SC-1 dst)
  {
    f32x4 acc = {0.f, 0.f, 0.f, 0.f};
    const unsigned short* bp = wsb + r * 128 + quad * 8;
#pragma unroll
    for (int t = 0; t < 4; ++t) {
      bf16x8 b = *(const bf16x8*)(bp + t * 32);
      acc = __builtin_amdgcn_mfma_f32_16x16x32_bf16(a[t], b, acc, 0, 0, 0);
    }
    int row = row0 + quad * 4;
    if (r < SC) {
#pragma unroll
      for (int i = 0; i < 4; ++i) ssrc[(size_t)(row + i) * SC + r] = acc[i];
    } else if (r < 2 * SC) {
#pragma unroll
      for (int i = 0; i < 4; ++i) sdst[(size_t)(row + i) * SC + (r - SC)] = acc[i];
    }
  }
}

// ---- K2: bucket sort (from strided bkt2) || gemm1 --------------------------
__global__ __launch_bounds__(256) void k_sort_gemm1(
    const unsigned* __restrict__ bkt2, int CAP, const int* __restrict__ cur,
    unsigned* __restrict__ csr4, int* __restrict__ rowptr, int N, int ET,
    int NBKT,
    const float* __restrict__ x, const unsigned short* __restrict__ W1t,
    const unsigned short* __restrict__ wsb1, unsigned short* __restrict__ h1b,
    float* __restrict__ ssrc1, float* __restrict__ sdst1) {
  if ((int)blockIdx.x >= NBKT) {
    int row0 = ((int)blockIdx.x - NBKT) * 64 + (threadIdx.x >> 6) * 16;
    if (row0 >= N) return;
    gemm_body<1, 4>(x, W1t, wsb1, h1b, ssrc1, sdst1, 128, row0);
    return;
  }
  __shared__ int s[256];
  __shared__ int cnt[256];
  int b = blockIdx.x, tid = threadIdx.x;
  int tot = cur[tid];  // per-bucket totals (buckets >= NBKT stayed 0)
  (void)lds_scan256(tot, s);  // s[i] = inclusive sum -> csr4 bases
  int base = (b == 0) ? 0 : s[b - 1];
  int tb = s[b] - base;
  const unsigned* src = bkt2 + (size_t)b * CAP;
  __syncthreads();
  cnt[tid] = 0;
  __syncthreads();
  for (int k = tid; k < tb; k += 512) {
    unsigned p0 = src[k];
    int k1 = k + 256;
    unsigned p1 = (k1 < tb) ? src[k1] : 0u;
    atomicAdd(&cnt[p0 >> 16], 1);
    if (k1 < tb) atomicAdd(&cnt[p1 >> 16], 1);
  }
  __syncthreads();
  int v = cnt[tid];
  int incl = lds_scan256(v, s);
  int excl = incl - v;
  int node = (b << 8) + tid;
  if (node < N) rowptr[node] = base + excl;
  if (tid == 0 && b == NBKT - 1) rowptr[N] = ET;
  cnt[tid] = base + excl;  // becomes the scatter cursor
  __syncthreads();
  for (int k = tid; k < tb; k += 512) {
    unsigned p0 = src[k];
    int k1 = k + 256;
    unsigned p1 = (k1 < tb) ? src[k1] : 0u;
    int slot0 = atomicAdd(&cnt[p0 >> 16], 1);
    csr4[slot0] = p0;
    if (k1 < tb) {
      int slot1 = atomicAdd(&cnt[p1 >> 16], 1);
      csr4[slot1] = p1;
    }
  }
}

// ---- fused layer-1 aggregation + layer-2 GEMM (1024 threads) ---------------
// Block = 16 waves = 16 nodes, ONE node per wave. Aggregation is a D=6
// preload-then-consume pipeline: 6 shfl'd packets -> 12 back-to-back loads
// -> predicated consume (order identical to the sequential loop). Tail for
// cnt > 24 uses the uniform-trip shfl loop. Then LDS stage + gemm2 tile.
__global__ __launch_bounds__(1024, 8) void gat_aggr1_gemm2(
    const int* __restrict__ rowptr, const unsigned* __restrict__ csr4,
    const float* __restrict__ ssrc, const float* __restrict__ sdst,
    const unsigned short* __restrict__ h, const float* __restrict__ bias,
    const unsigned short* __restrict__ W2t, const unsigned short* __restrict__ wsb2,
    unsigned short* __restrict__ h2b, float* __restrict__ ssrc2,
    float* __restrict__ sdst2, int N) {
  const int HC = 128, L = 16, G = 4, D = 6;  // D*G = 24 edges covered
  __shared__ unsigned short sm[16][136];  // +8 pad: 272B stride, 2-way banks
  int lane = threadIdx.x & 63;
  int wv = threadIdx.x >> 6;  // 0..15
  int base = blockIdx.x * 16;
  int l = lane & (L - 1);
  int g = lane / L;
  int c0 = l * 8;
  int hh = c0 >> 5;  // c0 / 32
  int n = base + wv;

  if (n < N) {
    int beg = rowptr[n];
    int cnt = rowptr[n + 1] - beg;
    float sdn = sdst[(size_t)n * 4 + hh];
    unsigned ce = 0;
    if (lane < cnt) ce = csr4[beg + lane];
    float a0 = 0.f, a1 = 0.f, a2 = 0.f, a3 = 0.f;
    float a4 = 0.f, a5 = 0.f, a6 = 0.f, a7 = 0.f, ws = 0.f;

    // ---- pipeline: preload D edges' scores + h rows ----
    int se[D]; float sc[D]; uint4 hv[D];
#pragma unroll
    for (int k = 0; k < D; ++k) {
      int j = g + k * G;                    // <= 23 < 64
      unsigned p = __shfl(ce, j, 64);       // uniform exec
      se[k] = (int)(p & 0xFFFF);            // invalid slots: ce=0 -> row 0 (hot)
    }
#pragma unroll
    for (int k = 0; k < D; ++k) sc[k] = ssrc[(size_t)se[k] * 4 + hh];
#pragma unroll
    for (int k = 0; k < D; ++k) hv[k] = *(const uint4*)(h + (size_t)se[k] * HC + c0);
#pragma unroll
    for (int k = 0; k < D; ++k) {
      int j = g + k * G;
      if (j < cnt) {
        float e = sc[k] + sdn;
        e = e > 0.f ? e : 0.2f * e;
        float w = __expf(e);
        uint4 u = hv[k];
        a0 = fmaf(w, bflo(u.x), a0); a1 = fmaf(w, bfhi(u.x), a1);
        a2 = fmaf(w, bflo(u.y), a2); a3 = fmaf(w, bfhi(u.y), a3);
        a4 = fmaf(w, bflo(u.z), a4); a5 = fmaf(w, bfhi(u.z), a5);
        a6 = fmaf(w, bflo(u.w), a6); a7 = fmaf(w, bfhi(u.w), a7);
        ws += w;
      }
    }
    // ---- tail: cnt > D*G (rare, ~4%) ----
    int T = (cnt + G - 1) / G;  // wave-uniform
    for (int k = D; k < T; ++k) {
      int j = g + k * G;
      unsigned p = __shfl(ce, j & 63, 64);  // uniform exec
      if (j < cnt) {
        if (j >= 64) p = csr4[beg + j];
        int s = (int)(p & 0xFFFF);
        float e = ssrc[(size_t)s * 4 + hh] + sdn;
        e = e > 0.f ? e : 0.2f * e;
        float w = __expf(e);
        uint4 u = *(const uint4*)(h + (size_t)s * HC + c0);
        a0 = fmaf(w, bflo(u.x), a0); a1 = fmaf(w, bfhi(u.x), a1);
        a2 = fmaf(w, bflo(u.y), a2); a3 = fmaf(w, bfhi(u.y), a3);
        a4 = fmaf(w, bflo(u.z), a4); a5 = fmaf(w, bfhi(u.z), a5);
        a6 = fmaf(w, bflo(u.w), a6); a7 = fmaf(w, bfhi(u.w), a7);
        ws += w;
      }
    }
#pragma unroll
    for (int off = L; off < 64; off <<= 1) {
      a0 += __shfl_xor(a0, off, 64); a1 += __shfl_xor(a1, off, 64);
      a2 += __shfl_xor(a2, off, 64); a3 += __shfl_xor(a3, off, 64);
      a4 += __shfl_xor(a4, off, 64); a5 += __shfl_xor(a5, off, 64);
      a6 += __shfl_xor(a6, off, 64); a7 += __shfl_xor(a7, off, 64);
      ws += __shfl_xor(ws, off, 64);
    }
    if (lane < L) {
      float inv = 1.f / ws;
      float4 bA = *(const float4*)(bias + c0);
      float4 bB = *(const float4*)(bias + c0 + 4);
      float v0 = fmaxf(fmaf(a0, inv, bA.x), 0.f);
      float v1 = fmaxf(fmaf(a1, inv, bA.y), 0.f);
      float v2 = fmaxf(fmaf(a2, inv, bA.z), 0.f);
      float v3 = fmaxf(fmaf(a3, inv, bA.w), 0.f);
      float v4 = fmaxf(fmaf(a4, inv, bB.x), 0.f);
      float v5 = fmaxf(fmaf(a5, inv, bB.y), 0.f);
      float v6 = fmaxf(fmaf(a6, inv, bB.z), 0.f);
      float v7 = fmaxf(fmaf(a7, inv, bB.w), 0.f);
      uint4 o;
      o.x = (unsigned)f2bf(v0) | ((unsigned)f2bf(v1) << 16);
      o.y = (unsigned)f2bf(v2) | ((unsigned)f2bf(v3) << 16);
      o.z = (unsigned)f2bf(v4) | ((unsigned)f2bf(v5) << 16);
      o.w = (unsigned)f2bf(v6) | ((unsigned)f2bf(v7) << 16);
      *(uint4*)&sm[wv][c0] = o;
    }
  } else if (lane < L) {
    *(uint4*)&sm[wv][c0] = make_uint4(0, 0, 0, 0);
  }
  __syncthreads();

  if (wv >= 5) return;
  // gemm2 from LDS: A = sm rows 0..15 (K=128)
  int r = lane & 15, quad = lane >> 4;
  bf16x8 a[4];
#pragma unroll
  for (int t = 0; t < 4; ++t) a[t] = *(const bf16x8*)&sm[r][quad * 8 + t * 32];
  if (wv < 4) {
    f32x4 acc = {0.f, 0.f, 0.f, 0.f};
    const unsigned short* bp = W2t + (size_t)(wv * 16 + r) * 128 + quad * 8;
#pragma unroll
    for (int t = 0; t < 4; ++t) {
      bf16x8 b = *(const bf16x8*)(bp + t * 32);
      acc = __builtin_amdgcn_mfma_f32_16x16x32_bf16(a[t], b, acc, 0, 0, 0);
    }
    unsigned short* cp = h2b + (size_t)(base + quad * 4) * 64 + wv * 16 + r;
#pragma unroll
    for (int i = 0; i < 4; ++i)
      if (base + quad * 4 + i < N) cp[(size_t)i * 64] = f2bf(acc[i]);
  } else {  // wv == 4: score tile
    f32x4 acc = {0.f, 0.f, 0.f, 0.f};
    const unsigned short* bp = wsb2 + r * 128 + quad * 8;
#pragma unroll
    for (int t = 0; t < 4; ++t) {
      bf16x8 b = *(const bf16x8*)(bp + t * 32);
      acc = __builtin_amdgcn_mfma_f32_16x16x32_bf16(a[t], b, acc, 0, 0, 0);
    }
    int row = base + quad * 4;
    if (r == 0) {
#pragma unroll
      for (int i = 0; i < 4; ++i) if (row + i < N) ssrc2[row + i] = acc[i];
    } else if (r == 1) {
#pragma unroll
      for (int i = 0; i < 4; ++i) if (row + i < N) sdst2[row + i] = acc[i];
    }
  }
}

// ---- layer-2 aggregator: D=3 preload pipeline (L=8, G=8, 128B/edge) --------
__global__ __launch_bounds__(256) void gat_aggr2(
    const int* __restrict__ rowptr, const unsigned* __restrict__ csr4,
    const float* __restrict__ ssrc, const float* __restrict__ sdst,
    const unsigned short* __restrict__ h, const float* __restrict__ bias,
    float* __restrict__ outv, int N) {
  const int HC = 64, L = 8, G = 8, D = 3;  // D*G = 24 edges covered
  int lane = threadIdx.x & 63;
  int n = blockIdx.x * 4 + (threadIdx.x >> 6);
  if (n >= N) return;
  int l = lane & (L - 1);
  int g = lane / L;  // 0..7
  int c0 = l * 8;
  int beg = rowptr[n];
  int cnt = rowptr[n + 1] - beg;
  float sdn = sdst[n];

  unsigned ce = 0;
  if (lane < cnt) ce = csr4[beg + lane];

  float a0 = 0.f, a1 = 0.f, a2 = 0.f, a3 = 0.f;
  float a4 = 0.f, a5 = 0.f, a6 = 0.f, a7 = 0.f, ws = 0.f;

  // ---- pipeline: preload D edges ----
  int se[D]; float sc[D]; uint4 hv[D];
#pragma unroll
  for (int k = 0; k < D; ++k) {
    int j = g + k * G;                    // <= 23 < 64
    unsigned p = __shfl(ce, j, 64);
    se[k] = (int)(p & 0xFFFF);
  }
#pragma unroll
  for (int k = 0; k < D; ++k) sc[k] = ssrc[se[k]];
#pragma unroll
  for (int k = 0; k < D; ++k) hv[k] = *(const uint4*)(h + (size_t)se[k] * HC + c0);
#pragma unroll
  for (int k = 0; k < D; ++k) {
    int j = g + k * G;
    if (j < cnt) {
      float e = sc[k] + sdn;
      e = e > 0.f ? e : 0.2f * e;
      float w = __expf(e);
      uint4 u = hv[k];
      a0 = fmaf(w, bflo(u.x), a0); a1 = fmaf(w, bfhi(u.x), a1);
      a2 = fmaf(w, bflo(u.y), a2); a3 = fmaf(w, bfhi(u.y), a3);
      a4 = fmaf(w, bflo(u.z), a4); a5 = fmaf(w, bfhi(u.z), a5);
      a6 = fmaf(w, bflo(u.w), a6); a7 = fmaf(w, bfhi(u.w), a7);
      ws += w;
    }
  }
  // ---- tail: cnt > 24 (rare) ----
  int T = (cnt + G - 1) / G;  // wave-uniform
  for (int k = D; k < T; ++k) {
    int j = g + k * G;
    unsigned p = __shfl(ce, j & 63, 64);
    if (j < cnt) {
      if (j >= 64) p = csr4[beg + j];
      int s = (int)(p & 0xFFFF);
      float e = ssrc[s] + sdn;
      e = e > 0.f ? e : 0.2f * e;
      float w = __expf(e);
      uint4 u = *(const uint4*)(h + (size_t)s * HC + c0);
      a0 = fmaf(w, bflo(u.x), a0); a1 = fmaf(w, bfhi(u.x), a1);
      a2 = fmaf(w, bflo(u.y), a2); a3 = fmaf(w, bfhi(u.y), a3);
      a4 = fmaf(w, bflo(u.z), a4); a5 = fmaf(w, bfhi(u.z), a5);
      a6 = fmaf(w, bflo(u.w), a6); a7 = fmaf(w, bfhi(u.w), a7);
      ws += w;
    }
  }

#pragma unroll
  for (int off = L; off < 64; off <<= 1) {
    a0 += __shfl_xor(a0, off, 64); a1 += __shfl_xor(a1, off, 64);
    a2 += __shfl_xor(a2, off, 64); a3 += __shfl_xor(a3, off, 64);
    a4 += __shfl_xor(a4, off, 64); a5 += __shfl_xor(a5, off, 64);
    a6 += __shfl_xor(a6, off, 64); a7 += __shfl_xor(a7, off, 64);
    ws += __shfl_xor(ws, off, 64);
  }
  if (lane < L) {
    float inv = 1.f / ws;  // self-loop guarantees ws > 0
    float4 bA = *(const float4*)(bias + c0);
    float4 bB = *(const float4*)(bias + c0 + 4);
    float v0 = fmaf(a0, inv, bA.x), v1 = fmaf(a1, inv, bA.y);
    float v2 = fmaf(a2, inv, bA.z), v3 = fmaf(a3, inv, bA.w);
    float v4 = fmaf(a4, inv, bB.x), v5 = fmaf(a5, inv, bB.y);
    float v6 = fmaf(a6, inv, bB.z), v7 = fmaf(a7, inv, bB.w);
    float* op = outv + (size_t)n * HC + c0;
    *(float4*)op = make_float4(v0, v1, v2, v3);
    *(float4*)(op + 4) = make_float4(v4, v5, v6, v7);
  }
}

extern "C" void kernel_launch(void* const* d_in, const int* in_sizes, int n_in,
                              void* d_out, int out_size, void* d_ws, size_t ws_size,
                              hipStream_t stream) {
  const float* x   = (const float*)d_in[0];
  const int*   ei  = (const int*)d_in[1];
  const float* W1  = (const float*)d_in[2];
  const float* as1 = (const float*)d_in[3];
  const float* ad1 = (const float*)d_in[4];
  const float* b1  = (const float*)d_in[5];
  const float* W2  = (const float*)d_in[6];
  const float* as2 = (const float*)d_in[7];
  const float* ad2 = (const float*)d_in[8];
  const float* b2  = (const float*)d_in[9];

  const int N = in_sizes[0] / 128;  // 50000
  const int E = in_sizes[1] / 2;    // 800000
  const int ET = E + N;
  const int NBKT = (N + 255) >> 8;              // 196
  const int NBLK = (ET + BCHUNK - 1) / BCHUNK;  // 831
  const int CAP = 6144;                         // per-bucket capacity in bkt2

  char* pc = (char*)d_ws;
  auto alloc = [&](size_t bytes) -> void* {
    void* r = (void*)pc;
    pc += (bytes + 255) & ~(size_t)255;
    return r;
  };
  unsigned short* h1b   = (unsigned short*)alloc((size_t)N * 128 * 2);
  unsigned short* h2b   = (unsigned short*)alloc((size_t)N * 64 * 2);  // un-aliased
  unsigned short* W1t   = (unsigned short*)alloc(128 * 128 * 2);
  unsigned short* W2t   = (unsigned short*)alloc(64 * 128 * 2);
  unsigned short* wsb1  = (unsigned short*)alloc(16 * 128 * 2);
  unsigned short* wsb2  = (unsigned short*)alloc(16 * 128 * 2);
  float* ssrc1 = (float*)alloc((size_t)N * 4 * 4);
  float* sdst1 = (float*)alloc((size_t)N * 4 * 4);
  float* ssrc2 = (float*)alloc((size_t)N * 4);
  float* sdst2 = (float*)alloc((size_t)N * 4);
  int* rowptr = (int*)alloc((size_t)(N + 1) * 4);
  int* cur    = (int*)alloc(256 * 4);
  unsigned* bkt2 = (unsigned*)alloc((size_t)256 * CAP * 4);
  unsigned* csr4 = (unsigned*)alloc((size_t)ET * 4);

  dim3 blk(256);
  const int GB = (N + 63) / 64;  // 782 gemm blocks

  // zero the bucket cursors (workspace arrives poisoned each iteration)
  hipMemsetAsync(cur, 0, 256 * sizeof(int), stream);

  // ---- K1: binned scatter (count+scan+scatter merged) + weight conversion --
  b_scatter_cvt<<<dim3(NBLK + 112), blk, 0, stream>>>(
      ei, E, N, NBLK, CAP, cur, bkt2,
      W1, as1, ad1, W2, as2, ad2, W1t, W2t, wsb1, wsb2);

  // ---- K2: bucket sort || full gemm1 ---------------------------------------
  k_sort_gemm1<<<dim3(NBKT + GB), blk, 0, stream>>>(
      bkt2, CAP, cur, csr4, rowptr, N, ET, NBKT,
      x, W1t, wsb1, h1b, ssrc1, sdst1);

  // ---- fused: layer-1 aggregation + gemm2 (+scores2), 1024-thread blocks ---
  gat_aggr1_gemm2<<<dim3((N + 15) / 16), dim3(1024), 0, stream>>>(
      rowptr, csr4, ssrc1, sdst1, h1b, b1, W2t, wsb2, h2b, ssrc2, sdst2, N);

  // ---- layer 2 aggregation: 1 head x 64, +bias (f32 out) -------------------
  gat_aggr2<<<dim3((N + 3) / 4), blk, 0, stream>>>(
      rowptr, csr4, ssrc2, sdst2, h2b, b2, (float*)d_out, N);
}